// Round 13
// baseline (513.493 us; speedup 1.0000x reference)
//
#include <hip/hip_runtime.h>

#define NN 50000
#define E_EDGES 800000
#define F_INN 128
#define HIDD 128
#define HEADS 8
#define CDIM 16
#define NCLS 10
#define NGG 64
#define NCONV 3
#define EPSS 1e-5f
#define NEG_SLOPE 0.2f

// Wt layout: per layer 144 rows (output cols) x 128 k, bf16.
// rows 0..127 = W' (BN-folded, transposed); 128..135 = alpha_src; 136..143 = alpha_dst.
#define WROWS 144
#define WSTRIDE (WROWS * 128)
#define BSTRIDE 144

// bucket partition: 128 dst nodes per bucket
#define BSH 7
#define BSZ 128
#define NB ((NN + BSZ - 1) / BSZ)   // 391
#define STAGE_CAP 16
#define BIN_BLOCKS 256
#define BIN_CHUNK (E_EDGES / BIN_BLOCKS)   // 3125 exact
#define SORT_BUF 4608
#define BUCKET_PAD 896
#define PW_KCH 32
#define GTILES ((NN + 127) / 128)   // 391 blocks, 2 row-tiles/wave

// MEASUREMENT ROUND: conv-core kernels (4 GEMMs + 3 aggregates) are launched
// TWICE each (idempotent). dur_us - 353 - ~12us gaps = true conv-core cost.
#define MEASURE_DUP 1

typedef __attribute__((ext_vector_type(8))) short short8;
typedef __attribute__((ext_vector_type(4))) float f32x4;
typedef __attribute__((ext_vector_type(2))) float f32x2;

__device__ __forceinline__ float lrelu(float x) { return x > 0.f ? x : NEG_SLOPE * x; }

__device__ __forceinline__ float bf2f(ushort u) {
    union { unsigned int i; float f; } v;
    v.i = ((unsigned int)u) << 16;
    return v.f;
}
__device__ __forceinline__ ushort f2bf(float f) {
    union { float f; unsigned int i; } v;
    v.f = f;
    unsigned int r = (v.i + 0x7fffu + ((v.i >> 16) & 1u)) >> 16;  // RNE
    return (ushort)r;
}
// OCP e4m3 encode via HW pack (saturating); take byte 0
__device__ __forceinline__ unsigned char f2fp8(float f) {
    int r = __builtin_amdgcn_cvt_pk_fp8_f32(f, f, 0, false);
    return (unsigned char)(r & 0xff);
}

// ================================================================ prep_all (+hist) [R11-proven]
__global__ __launch_bounds__(256) void prep_all(
    const float* __restrict__ bn_feat, const float* __restrict__ w_feat,
    const float* __restrict__ b_feat, const float* __restrict__ bns_conv,
    const float* __restrict__ gat_w, const float* __restrict__ att_src,
    const float* __restrict__ att_dst, const int* __restrict__ dst,
    ushort* __restrict__ Wt, float* __restrict__ bp, int* __restrict__ bcnt)
{
    __shared__ __align__(16) char smem[18560];
    int blk = blockIdx.x;
    int t = threadIdx.x;

    if (blk < 16) {
        float* Wl = (float*)smem;            // 32*129 floats
        float* aak = Wl + PW_KCH * 129;      // 32 floats
        int layer = blk >> 2;
        int k0 = (blk & 3) * PW_KCH;
        const float* bn; const float* W;
        if (layer == 0) { bn = bn_feat; W = w_feat; }
        else { bn = bns_conv + (layer - 1) * 4 * HIDD; W = gat_w + (size_t)(layer - 1) * HIDD * HIDD; }
        if (t < PW_KCH) {
            int k = k0 + t;
            aak[t] = bn[k] * rsqrtf(bn[3 * HIDD + k] + EPSS);
        }
        for (int i = t; i < PW_KCH * 128; i += 256) {
            int kk = i >> 7, n = i & 127;
            Wl[kk * 129 + n] = W[(size_t)(k0 + kk) * 128 + n];
        }
        __syncthreads();
        ushort* wrow = Wt + (size_t)layer * WSTRIDE;
        for (int i = t; i < 128 * PW_KCH; i += 256) {
            int n = i >> 5, kk = i & 31;
            wrow[n * 128 + k0 + kk] = f2bf(aak[kk] * Wl[kk * 129 + n]);
        }
    } else if (blk < 20) {
        float* ccs = (float*)smem;
        int layer = blk - 16;
        const float* bn; const float* W;
        if (layer == 0) { bn = bn_feat; W = w_feat; }
        else { bn = bns_conv + (layer - 1) * 4 * HIDD; W = gat_w + (size_t)(layer - 1) * HIDD * HIDD; }
        if (t < 128) {
            float a = bn[t] * rsqrtf(bn[3 * HIDD + t] + EPSS);
            ccs[t] = bn[HIDD + t] - bn[2 * HIDD + t] * a;
        }
        __syncthreads();
        if (t < 128) {
            float bacc = (layer == 0) ? b_feat[t] : 0.f;
            for (int k = 0; k < 128; ++k) bacc += ccs[k] * W[(size_t)k * 128 + t];
            bp[layer * BSTRIDE + t] = bacc;
        }
    } else if (blk < 23) {
        float* Wl   = (float*)smem;               // 32*129 floats (16512 B)
        float* redS = (float*)(smem + 16512);     // 256 floats
        float* redD = redS + 256;                 // 256 floats
        int li = blk - 20;
        int L = li + 1;
        const float* bn = bns_conv + li * 4 * HIDD;
        const float* W  = gat_w + (size_t)li * HIDD * HIDD;
        const float* as = att_src + li * HEADS * CDIM;
        const float* ad = att_dst + li * HEADS * CDIM;
        ushort* Wo = Wt + (size_t)L * WSTRIDE;
        int kl = t >> 3, h = t & 7;
        float acc_s = 0.f, acc_d = 0.f;
        for (int c0 = 0; c0 < 4; ++c0) {
            int k0 = c0 * 32;
            __syncthreads();
            for (int i = t; i < 32 * 128; i += 256) {
                int kk = i >> 7, n = i & 127;
                Wl[kk * 129 + n] = W[(size_t)(k0 + kk) * 128 + n];
            }
            __syncthreads();
            int k = k0 + kl;
            float a  = bn[k] * rsqrtf(bn[3 * HIDD + k] + EPSS);
            float cc = bn[HIDD + k] - bn[2 * HIDD + k] * a;
            float ps = 0.f, pd = 0.f;
            #pragma unroll
            for (int c = 0; c < 16; ++c) {
                float wv = Wl[kl * 129 + h * 16 + c];
                ps += wv * as[h * 16 + c];
                pd += wv * ad[h * 16 + c];
            }
            Wo[(128 + h) * 128 + k] = f2bf(a * ps);
            Wo[(136 + h) * 128 + k] = f2bf(a * pd);
            acc_s += cc * ps;
            acc_d += cc * pd;
        }
        redS[t] = acc_s; redD[t] = acc_d;
        __syncthreads();
        if (t < 8) {
            float s = 0.f, d = 0.f;
            for (int q = 0; q < 32; ++q) { s += redS[q * 8 + t]; d += redD[q * 8 + t]; }
            bp[L * BSTRIDE + 128 + t] = s;
            bp[L * BSTRIDE + 136 + t] = d;
        }
    } else {
        int* hh = (int*)smem;
        for (int i = t; i < NB; i += 256) hh[i] = 0;
        __syncthreads();
        int cblk = blk - 23;
        for (int e = cblk * 256 + t; e < E_EDGES; e += 256 * 256)
            atomicAdd(&hh[dst[e] >> BSH], 1);
        __syncthreads();
        for (int i = t; i < NB; i += 256)
            if (hh[i]) atomicAdd(&bcnt[i], hh[i]);
    }
}

// ================================================================ CSR build (R7-proven)
__global__ __launch_bounds__(512) void bucket_scan(const int* __restrict__ bcnt,
    int* __restrict__ bbase_pad, int* __restrict__ bpos, int* __restrict__ bout)
{
    __shared__ int s2[512], s3[512];
    int t = threadIdx.x;
    int c = (t < NB) ? bcnt[t] : 0;
    int p = (c + 15) & ~15;
    int q = (c + BUCKET_PAD + 7) & ~7;
    s2[t] = p; s3[t] = q;
    __syncthreads();
    for (int d = 1; d < 512; d <<= 1) {
        int a2 = (t >= d) ? s2[t - d] : 0;
        int a3 = (t >= d) ? s3[t - d] : 0;
        __syncthreads();
        s2[t] += a2; s3[t] += a3;
        __syncthreads();
    }
    if (t < NB) {
        int b2 = s2[t] - p;
        bbase_pad[t] = b2;
        bpos[t] = b2;
        bout[t] = s3[t] - q;
    }
}

__global__ __launch_bounds__(256) void bin_edges(const int* __restrict__ src,
    const int* __restrict__ dst, int* __restrict__ bpos, unsigned int* __restrict__ tmp)
{
    __shared__ unsigned int stage[NB * STAGE_CAP];  // ~25 KB
    __shared__ int scnt[NB];
    int t = threadIdx.x;
    for (int i = t; i < NB; i += 256) scnt[i] = 0;
    __syncthreads();
    int cbeg = blockIdx.x * BIN_CHUNK;
    int cend = cbeg + BIN_CHUNK;
    for (int tb = cbeg; tb < cend; tb += 256) {
        int e = tb + t;
        if (e < cend) {
            int d = dst[e];
            int b = d >> BSH;
            unsigned int pk = ((unsigned int)(d & (BSZ - 1)) << 16) | (unsigned int)src[e];
            int slot = atomicAdd(&scnt[b], 1);
            if (slot < STAGE_CAP) stage[b * STAGE_CAP + slot] = pk;
            else { int g = atomicAdd(&bpos[b], 1); tmp[g] = pk; }
        }
        __syncthreads();
        for (int b = t; b < NB; b += 256) {
            if (scnt[b] >= STAGE_CAP) {
                int g = atomicAdd(&bpos[b], STAGE_CAP);
                #pragma unroll
                for (int j = 0; j < STAGE_CAP; ++j) tmp[g + j] = stage[b * STAGE_CAP + j];
                scnt[b] = 0;
            }
        }
        __syncthreads();
    }
    for (int b = t; b < NB; b += 256) {
        int n = scnt[b];
        if (n > 0) {
            int g = atomicAdd(&bpos[b], n);
            for (int j = 0; j < n; ++j) tmp[g + j] = stage[b * STAGE_CAP + j];
        }
    }
}

__global__ __launch_bounds__(256) void bucket_sort(const int* __restrict__ bcnt,
    const int* __restrict__ bbase_pad, const int* __restrict__ bout,
    const unsigned int* __restrict__ tmp, ushort* __restrict__ csr,
    unsigned int* __restrict__ rowptr)
{
    __shared__ unsigned int buf[SORT_BUF];
    __shared__ int hist[BSZ];
    __shared__ int pex[BSZ];
    __shared__ int cur[BSZ];
    int b = blockIdx.x, t = threadIdx.x;
    int m = bcnt[b];
    if (m > SORT_BUF) m = SORT_BUF;
    int base_in = bbase_pad[b], base_out = bout[b];
    if (t < BSZ) hist[t] = 0;
    __syncthreads();
    for (int i = t; i < m; i += 256) {
        unsigned int pk = tmp[base_in + i];
        buf[i] = pk;
        atomicAdd(&hist[pk >> 16], 1);
    }
    __syncthreads();
    int pd = 0;
    if (t < BSZ) { pd = (hist[t] + 7) & ~7; pex[t] = pd; }
    __syncthreads();
    for (int d = 1; d < BSZ; d <<= 1) {
        int a = (t < BSZ && t >= d) ? pex[t - d] : 0;
        __syncthreads();
        if (t < BSZ) pex[t] += a;
        __syncthreads();
    }
    if (t < BSZ) {
        int ex = pex[t] - pd;
        pex[t] = ex;
        cur[t] = ex;
        int node = b * BSZ + t;
        if (node < NN)
            rowptr[node] = (unsigned int)(base_out + ex) | ((unsigned int)hist[t] << 21);
    }
    __syncthreads();
    for (int i = t; i < m; i += 256) {
        unsigned int pk = buf[i];
        int dl = pk >> 16;
        int p = atomicAdd(&cur[dl], 1);
        csr[base_out + p] = (ushort)(pk & 0xffffu);
    }
    __syncthreads();
    if (t < BSZ) {
        int ex = pex[t], hn = hist[t], pdn = (hn + 7) & ~7;
        for (int i = hn; i < pdn; ++i) csr[base_out + ex + i] = 0;
    }
}

// ================================================================ bf16 MFMA GEMM, 2 row-tiles/wave (R10-proven)
template <int F32IN, int ALPHAS>
__global__ __launch_bounds__(256) void gemm_mfma(const void* __restrict__ Ain,
    const ushort* __restrict__ Wt, const float* __restrict__ bias,
    ushort* __restrict__ Out, unsigned char* __restrict__ h8,
    float* __restrict__ alph_s, float* __restrict__ alph_d, int n, int dorelu)
{
    const int NT = ALPHAS ? 9 : 8;
    int t = threadIdx.x;
    int wave = t >> 6, lane = t & 63;
    int m16 = lane & 15, quad = lane >> 4;
    int rbase = blockIdx.x * 128 + wave * 32;

    short8 afrag[2][4];
    #pragma unroll
    for (int tt = 0; tt < 2; ++tt) {
        int arow_i = rbase + tt * 16 + m16;
        size_t arow = (size_t)(arow_i < n ? arow_i : 0) * HIDD + quad * 8;
        if (F32IN) {
            const float* ap = (const float*)Ain + arow;
            #pragma unroll
            for (int kk = 0; kk < 4; ++kk) {
                float4 lo = *(const float4*)(ap + kk * 32);
                float4 hi = *(const float4*)(ap + kk * 32 + 4);
                short8 f;
                f[0] = (short)f2bf(lo.x); f[1] = (short)f2bf(lo.y);
                f[2] = (short)f2bf(lo.z); f[3] = (short)f2bf(lo.w);
                f[4] = (short)f2bf(hi.x); f[5] = (short)f2bf(hi.y);
                f[6] = (short)f2bf(hi.z); f[7] = (short)f2bf(hi.w);
                afrag[tt][kk] = f;
            }
        } else {
            const ushort* ap = (const ushort*)Ain + arow;
            #pragma unroll
            for (int kk = 0; kk < 4; ++kk)
                afrag[tt][kk] = *(const short8*)(ap + kk * 32);
        }
    }

    f32x4 acc[2][9];
    #pragma unroll
    for (int tt = 0; tt < 2; ++tt)
        #pragma unroll
        for (int nt = 0; nt < NT; ++nt) acc[tt][nt] = (f32x4){0.f, 0.f, 0.f, 0.f};

    #pragma unroll
    for (int nt = 0; nt < NT; ++nt) {
        const ushort* brow = Wt + (size_t)(nt * 16 + m16) * HIDD + quad * 8;
        #pragma unroll
        for (int kk = 0; kk < 4; ++kk) {
            short8 bfrag = *(const short8*)(brow + kk * 32);
            acc[0][nt] = __builtin_amdgcn_mfma_f32_16x16x32_bf16(afrag[0][kk], bfrag, acc[0][nt], 0, 0, 0);
            acc[1][nt] = __builtin_amdgcn_mfma_f32_16x16x32_bf16(afrag[1][kk], bfrag, acc[1][nt], 0, 0, 0);
        }
    }

    #pragma unroll
    for (int tt = 0; tt < 2; ++tt) {
        int tb = rbase + tt * 16;
        #pragma unroll
        for (int nt = 0; nt < 8; ++nt) {
            int col = nt * 16 + m16;
            float bv = bias[col];
            #pragma unroll
            for (int r = 0; r < 4; ++r) {
                int orow = tb + quad * 4 + r;
                if (orow < n) {
                    float v = acc[tt][nt][r] + bv;
                    if (dorelu) v = fmaxf(v, 0.f);
                    Out[(size_t)orow * HIDD + col] = f2bf(v);
                    if (ALPHAS) h8[(size_t)orow * HIDD + col] = f2fp8(v);
                }
            }
        }
        if (ALPHAS) {
            float bv = bias[128 + m16];
            #pragma unroll
            for (int r = 0; r < 4; ++r) {
                int orow = tb + quad * 4 + r;
                if (orow < n) {
                    float v = acc[tt][8][r] + bv;
                    if (m16 < 8) alph_s[orow * HEADS + m16] = v;
                    else         alph_d[orow * HEADS + (m16 - 8)] = v;
                }
            }
        }
    }
}

// ================================================================ GAT aggregation (R12)
__global__ __launch_bounds__(256) void gat_aggregate(
    const ushort* __restrict__ h, const unsigned char* __restrict__ h8,
    const float* __restrict__ as, const float* __restrict__ ad,
    const unsigned int* __restrict__ rowptr, const ushort* __restrict__ csr,
    const float* __restrict__ bias, ushort* __restrict__ out)
{
    int wid = (blockIdx.x * 256 + threadIdx.x) >> 6;
    int v = __builtin_amdgcn_readfirstlane(wid);
    if (v >= NN) return;
    int lane = threadIdx.x & 63;
    int hd = lane >> 3;
    int slot = lane & 7;
    int gbase = lane & ~7;
    unsigned int rp = rowptr[v];
    int beg = rp & 0x1FFFFF;
    int cnt = rp >> 21;
    float adv = ad[v * HEADS + hd];

    const unsigned int* h32 = (const unsigned int*)h;
    const ushort* h8v = (const ushort*)h8;      // 2 fp8 channels per lane

    float wself = __expf(lrelu(as[v * HEADS + hd] + adv));
    unsigned int hv = h32[(size_t)v * 64 + lane];
    float acc0 = wself * bf2f((ushort)(hv & 0xffff));
    float acc1 = wself * bf2f((ushort)(hv >> 16));
    float wsum_own = 0.f;

    int ngro = (cnt + 7) >> 3;
    if (ngro > 0) {
        const uint4* epk = (const uint4*)(csr + beg);
        int u0[8], u1[8];
        float l_own0, l_own1;
        unsigned int x0[8], x1[8];
        {
            uint4 pk = epk[0];
            u0[0] = pk.x & 0xffff; u0[1] = pk.x >> 16;
            u0[2] = pk.y & 0xffff; u0[3] = pk.y >> 16;
            u0[4] = pk.z & 0xffff; u0[5] = pk.z >> 16;
            u0[6] = pk.w & 0xffff; u0[7] = pk.w >> 16;
            unsigned int d = slot < 4 ? (slot < 2 ? pk.x : pk.y)
                                      : (slot < 6 ? pk.z : pk.w);
            int u_own = (slot & 1) ? (int)(d >> 16) : (int)(d & 0xffff);
            l_own0 = as[u_own * HEADS + hd];
            #pragma unroll
            for (int j = 0; j < 8; ++j) x0[j] = h8v[(size_t)u0[j] * 64 + lane];
        }
        for (int g = 0; g < ngro; ++g) {
            bool more = (g + 1 < ngro);
            if (more) {
                uint4 pk = epk[g + 1];
                u1[0] = pk.x & 0xffff; u1[1] = pk.x >> 16;
                u1[2] = pk.y & 0xffff; u1[3] = pk.y >> 16;
                u1[4] = pk.z & 0xffff; u1[5] = pk.z >> 16;
                u1[6] = pk.w & 0xffff; u1[7] = pk.w >> 16;
                unsigned int d = slot < 4 ? (slot < 2 ? pk.x : pk.y)
                                          : (slot < 6 ? pk.z : pk.w);
                int u_own = (slot & 1) ? (int)(d >> 16) : (int)(d & 0xffff);
                l_own1 = as[u_own * HEADS + hd];
                #pragma unroll
                for (int j = 0; j < 8; ++j) x1[j] = h8v[(size_t)u1[j] * 64 + lane];
            }
            float w_own = __expf(lrelu(l_own0 + adv));
            if (g * 8 + slot >= cnt) w_own = 0.f;
            wsum_own += w_own;
            #pragma unroll
            for (int j = 0; j < 8; ++j) {
                float wj = __shfl(w_own, gbase + j, 64);
                f32x2 hv2 = __builtin_amdgcn_cvt_pk_f32_fp8((int)x0[j], false);
                acc0 += wj * hv2[0];
                acc1 += wj * hv2[1];
            }
            if (more) {
                l_own0 = l_own1;
                #pragma unroll
                for (int j = 0; j < 8; ++j) { u0[j] = u1[j]; x0[j] = x1[j]; }
            }
        }
    }

    #pragma unroll
    for (int off = 1; off < 8; off <<= 1) wsum_own += __shfl_xor(wsum_own, off);
    float denom = wself + wsum_own;

    float inv = 1.f / (denom + 1e-16f);
    int c = 2 * lane;
    float o0 = fmaxf(acc0 * inv + bias[c], 0.f);
    float o1 = fmaxf(acc1 * inv + bias[c + 1], 0.f);
    ((unsigned int*)out)[(size_t)v * 64 + lane] =
        (unsigned int)f2bf(o0) | ((unsigned int)f2bf(o1) << 16);
}

// ================================================================ pool + FC head (R6-proven fused)
__global__ __launch_bounds__(256) void pool_head(const ushort* __restrict__ h,
    const int* __restrict__ batch,
    const float* __restrict__ bns_fc, const float* __restrict__ fc_w,
    const float* __restrict__ fc_b, const float* __restrict__ bn_hid,
    const float* __restrict__ w_class, const float* __restrict__ b_class,
    float* __restrict__ out)
{
    __shared__ float sred[256];
    __shared__ float v1[HIDD];
    __shared__ float v2[HIDD];
    __shared__ float lg[NCLS];
    __shared__ float lse;
    __shared__ int bounds[2];
    int gb = blockIdx.x, t = threadIdx.x;

    if (t < 2) {
        int key = gb + t;
        int lo = 0, hi = NN;
        while (lo < hi) {
            int mid = (lo + hi) >> 1;
            if (batch[mid] < key) lo = mid + 1; else hi = mid;
        }
        bounds[t] = lo;
    }
    __syncthreads();
    int beg = bounds[0], end = bounds[1];

    int half = t >> 7, c = t & 127;
    float a0 = 0.f, a1 = 0.f, a2 = 0.f, a3 = 0.f;
    int r = beg + half;
    for (; r + 6 < end; r += 8) {
        a0 += bf2f(h[(size_t)r * HIDD + c]);
        a1 += bf2f(h[(size_t)(r + 2) * HIDD + c]);
        a2 += bf2f(h[(size_t)(r + 4) * HIDD + c]);
        a3 += bf2f(h[(size_t)(r + 6) * HIDD + c]);
    }
    for (; r < end; r += 2) a0 += bf2f(h[(size_t)r * HIDD + c]);
    sred[t] = (a0 + a1) + (a2 + a3);
    __syncthreads();

    if (t < HIDD) {
        float gv = sred[t] + sred[t + 128];
        float gamma = bns_fc[t], beta = bns_fc[HIDD + t];
        float mu = bns_fc[2 * HIDD + t], var = bns_fc[3 * HIDD + t];
        v1[t] = (gv - mu) * gamma * rsqrtf(var + EPSS) + beta;
    }
    __syncthreads();

    if (t < HIDD) {
        float acc = fc_b[t];
        for (int k = 0; k < HIDD; ++k) acc += v1[k] * fc_w[k * HIDD + t];
        acc = fmaxf(acc, 0.f);
        float gamma = bn_hid[t], beta = bn_hid[HIDD + t];
        float mu = bn_hid[2 * HIDD + t], var = bn_hid[3 * HIDD + t];
        v2[t] = (acc - mu) * gamma * rsqrtf(var + EPSS) + beta;
    }
    __syncthreads();

    if (t < NCLS) {
        float acc2 = b_class[t];
        for (int k = 0; k < HIDD; ++k) acc2 += v2[k] * w_class[k * NCLS + t];
        lg[t] = acc2;
    }
    __syncthreads();
    if (t == 0) {
        float mx = lg[0];
        for (int i = 1; i < NCLS; ++i) mx = fmaxf(mx, lg[i]);
        float ss = 0.f;
        for (int i = 0; i < NCLS; ++i) ss += __expf(lg[i] - mx);
        lse = mx + __logf(ss);
    }
    __syncthreads();
    if (t < NCLS) out[gb * NCLS + t] = lg[t] - lse;
}

// ================================================================ launch
extern "C" void kernel_launch(void* const* d_in, const int* in_sizes, int n_in,
                              void* d_out, int out_size, void* d_ws, size_t ws_size,
                              hipStream_t stream)
{
    const float* x        = (const float*)d_in[0];
    const int*   edge     = (const int*)d_in[1];
    const int*   batch    = (const int*)d_in[2];
    const float* bn_feat  = (const float*)d_in[3];
    const float* w_feat   = (const float*)d_in[4];
    const float* b_feat   = (const float*)d_in[5];
    const float* bns_conv = (const float*)d_in[6];
    const float* gat_w    = (const float*)d_in[7];
    const float* att_src  = (const float*)d_in[8];
    const float* att_dst  = (const float*)d_in[9];
    const float* gat_b    = (const float*)d_in[10];
    const float* bns_fc   = (const float*)d_in[11];
    const float* fc_w     = (const float*)d_in[12];
    const float* fc_b     = (const float*)d_in[13];
    const float* bn_hid   = (const float*)d_in[14];
    const float* w_class  = (const float*)d_in[15];
    const float* b_class  = (const float*)d_in[16];
    float* out = (float*)d_out;
    (void)in_sizes; (void)n_in; (void)out_size; (void)ws_size;

    char* ws = (char*)d_ws;
    size_t off = 0;
    auto alloc = [&](size_t bytes) {
        void* p = ws + off;
        off = (off + bytes + 255) & ~(size_t)255;
        return p;
    };
    ushort* Wt        = (ushort*)alloc((size_t)4 * WSTRIDE * sizeof(ushort));
    float*  bp        = (float*)alloc(4 * BSTRIDE * sizeof(float));
    ushort* h_a       = (ushort*)alloc((size_t)NN * HIDD * sizeof(ushort));
    ushort* h_b       = (ushort*)alloc((size_t)NN * HIDD * sizeof(ushort));
    unsigned char* h8 = (unsigned char*)alloc((size_t)NN * HIDD);
    float*  alph_s    = (float*)alloc((size_t)NN * HEADS * sizeof(float));
    float*  alph_d    = (float*)alloc((size_t)NN * HEADS * sizeof(float));
    int*    bcnt      = (int*)alloc(NB * sizeof(int));
    int*    bbase_pad = (int*)alloc(NB * sizeof(int));
    int*    bpos      = (int*)alloc(NB * sizeof(int));
    int*    bout      = (int*)alloc(NB * sizeof(int));
    unsigned int* tmp = (unsigned int*)alloc((size_t)(E_EDGES + NB * STAGE_CAP) * sizeof(unsigned int));
    unsigned int* rowptr = (unsigned int*)alloc((size_t)NN * sizeof(unsigned int));
    ushort* csr       = (ushort*)alloc((size_t)(E_EDGES + NB * BUCKET_PAD + 16) * sizeof(ushort));

    const int* src = edge;
    const int* dst = edge + E_EDGES;

    hipMemsetAsync(bcnt, 0, NB * sizeof(int), stream);
    prep_all<<<279, 256, 0, stream>>>(bn_feat, w_feat, b_feat, bns_conv, gat_w,
                                      att_src, att_dst, dst, Wt, bp, bcnt);
    bucket_scan<<<1, 512, 0, stream>>>(bcnt, bbase_pad, bpos, bout);
    bin_edges<<<BIN_BLOCKS, 256, 0, stream>>>(src, dst, bpos, tmp);
    bucket_sort<<<NB, 256, 0, stream>>>(bcnt, bbase_pad, bout, tmp, csr, rowptr);

    // h_a = relu(bn(x) @ w_feat + b_feat)   [x2: measurement]
    for (int rep = 0; rep < 1 + MEASURE_DUP; ++rep)
        gemm_mfma<1, 0><<<GTILES, 256, 0, stream>>>(x, Wt, bp, h_a,
            nullptr, nullptr, nullptr, NN, 1);

    for (int i = 0; i < NCONV; ++i) {
        for (int rep = 0; rep < 1 + MEASURE_DUP; ++rep)
            gemm_mfma<0, 1><<<GTILES, 256, 0, stream>>>(h_a,
                Wt + (size_t)(i + 1) * WSTRIDE, bp + (i + 1) * BSTRIDE, h_b, h8,
                alph_s, alph_d, NN, 0);
        for (int rep = 0; rep < 1 + MEASURE_DUP; ++rep)
            gat_aggregate<<<(NN + 3) / 4, 256, 0, stream>>>(h_b, h8, alph_s, alph_d,
                                                            rowptr, csr, gat_b + i * HIDD, h_a);
    }

    pool_head<<<NGG, 256, 0, stream>>>(h_a, batch, bns_fc, fc_w, fc_b, bn_hid,
                                       w_class, b_class, out);
}

// Round 14
// 325.963 us; speedup vs baseline: 1.5753x; 1.5753x over previous
//
#include <hip/hip_runtime.h>

#define NN 50000
#define E_EDGES 800000
#define F_INN 128
#define HIDD 128
#define HEADS 8
#define CDIM 16
#define NCLS 10
#define NGG 64
#define NCONV 3
#define EPSS 1e-5f
#define NEG_SLOPE 0.2f

// Wt layout: per layer 144 rows (output cols) x 128 k, bf16.
#define WROWS 144
#define WSTRIDE (WROWS * 128)
#define BSTRIDE 144

// bucket partition: 128 dst nodes per bucket
#define BSH 7
#define BSZ 128
#define NB ((NN + BSZ - 1) / BSZ)   // 391
#define BIN_BLOCKS 256
#define BIN_CHUNK (E_EDGES / BIN_BLOCKS)   // 3125 exact
#define TABW 392                     // 391 offsets + sentinel
#define CAPB 4608                    // fixed csr region/bucket: need <= cnt+896, cnt~2048
#define SORT_BUF 4608
#define PW_KCH 32
#define GTILES ((NN + 127) / 128)    // 391 gemm blocks (128 rows each)

typedef __attribute__((ext_vector_type(8))) short short8;
typedef __attribute__((ext_vector_type(4))) float f32x4;
typedef __attribute__((ext_vector_type(2))) float f32x2;

__device__ __forceinline__ float lrelu(float x) { return x > 0.f ? x : NEG_SLOPE * x; }

__device__ __forceinline__ float bf2f(ushort u) {
    union { unsigned int i; float f; } v;
    v.i = ((unsigned int)u) << 16;
    return v.f;
}
__device__ __forceinline__ ushort f2bf(float f) {
    union { float f; unsigned int i; } v;
    v.f = f;
    unsigned int r = (v.i + 0x7fffu + ((v.i >> 16) & 1u)) >> 16;  // RNE
    return (ushort)r;
}
// OCP e4m3 encode via HW pack (saturating); take byte 0
__device__ __forceinline__ unsigned char f2fp8(float f) {
    int r = __builtin_amdgcn_cvt_pk_fp8_f32(f, f, 0, false);
    return (unsigned char)(r & 0xff);
}

// ================================================================ GEMM core (device fn)
// Out[n,128] = A[n,128] @ W + bias; 2 row-tiles (32 rows)/wave, 128 rows/block.
// ALPHAS: 9th 16-col tile = alpha projections (fp32 out) + fp8 copy h8.
// mfma C layout: col=lane&15, row=quad*4+reg (verified m89).
template <int F32IN, int ALPHAS>
__device__ __forceinline__ void gemm_core(int tile, int t,
    const void* __restrict__ Ain, const ushort* __restrict__ Wt,
    const float* __restrict__ bias, ushort* __restrict__ Out,
    unsigned char* __restrict__ h8, float* __restrict__ alph_s,
    float* __restrict__ alph_d, int n, int dorelu)
{
    const int NT = ALPHAS ? 9 : 8;
    int wave = t >> 6, lane = t & 63;
    int m16 = lane & 15, quad = lane >> 4;
    int rbase = tile * 128 + wave * 32;

    short8 afrag[2][4];
    #pragma unroll
    for (int tt = 0; tt < 2; ++tt) {
        int arow_i = rbase + tt * 16 + m16;
        size_t arow = (size_t)(arow_i < n ? arow_i : 0) * HIDD + quad * 8;
        if (F32IN) {
            const float* ap = (const float*)Ain + arow;
            #pragma unroll
            for (int kk = 0; kk < 4; ++kk) {
                float4 lo = *(const float4*)(ap + kk * 32);
                float4 hi = *(const float4*)(ap + kk * 32 + 4);
                short8 f;
                f[0] = (short)f2bf(lo.x); f[1] = (short)f2bf(lo.y);
                f[2] = (short)f2bf(lo.z); f[3] = (short)f2bf(lo.w);
                f[4] = (short)f2bf(hi.x); f[5] = (short)f2bf(hi.y);
                f[6] = (short)f2bf(hi.z); f[7] = (short)f2bf(hi.w);
                afrag[tt][kk] = f;
            }
        } else {
            const ushort* ap = (const ushort*)Ain + arow;
            #pragma unroll
            for (int kk = 0; kk < 4; ++kk)
                afrag[tt][kk] = *(const short8*)(ap + kk * 32);
        }
    }

    f32x4 acc[2][9];
    #pragma unroll
    for (int tt = 0; tt < 2; ++tt)
        #pragma unroll
        for (int nt = 0; nt < NT; ++nt) acc[tt][nt] = (f32x4){0.f, 0.f, 0.f, 0.f};

    #pragma unroll
    for (int nt = 0; nt < NT; ++nt) {
        const ushort* brow = Wt + (size_t)(nt * 16 + m16) * HIDD + quad * 8;
        #pragma unroll
        for (int kk = 0; kk < 4; ++kk) {
            short8 bfrag = *(const short8*)(brow + kk * 32);
            acc[0][nt] = __builtin_amdgcn_mfma_f32_16x16x32_bf16(afrag[0][kk], bfrag, acc[0][nt], 0, 0, 0);
            acc[1][nt] = __builtin_amdgcn_mfma_f32_16x16x32_bf16(afrag[1][kk], bfrag, acc[1][nt], 0, 0, 0);
        }
    }

    #pragma unroll
    for (int tt = 0; tt < 2; ++tt) {
        int tb = rbase + tt * 16;
        #pragma unroll
        for (int nt = 0; nt < 8; ++nt) {
            int col = nt * 16 + m16;
            float bv = bias[col];
            #pragma unroll
            for (int r = 0; r < 4; ++r) {
                int orow = tb + quad * 4 + r;
                if (orow < n) {
                    float v = acc[tt][nt][r] + bv;
                    if (dorelu) v = fmaxf(v, 0.f);
                    Out[(size_t)orow * HIDD + col] = f2bf(v);
                    if (ALPHAS) h8[(size_t)orow * HIDD + col] = f2fp8(v);
                }
            }
        }
        if (ALPHAS) {
            float bv = bias[128 + m16];
            #pragma unroll
            for (int r = 0; r < 4; ++r) {
                int orow = tb + quad * 4 + r;
                if (orow < n) {
                    float v = acc[tt][8][r] + bv;
                    if (m16 < 8) alph_s[orow * HEADS + m16] = v;
                    else         alph_d[orow * HEADS + (m16 - 8)] = v;
                }
            }
        }
    }
}

// ================================================================ kernel A: prep + bin
// blocks 0-15 : Wt[n][k] = a_k*W[k][n]; 16-19: biases; 20-22: alpha cols;
// blocks 23-278: BIN block k=blk-23 — locally hist+scan+reorder its 3125 edges
// into private tmp region (coalesced), write offset table tab[k][0..391]
// (tab[k][b]=start of bucket-b segment in block k's region; [391]=3125).
// No cross-block atomics, no global scan dependency.
__global__ __launch_bounds__(256) void prep_bin(
    const float* __restrict__ bn_feat, const float* __restrict__ w_feat,
    const float* __restrict__ b_feat, const float* __restrict__ bns_conv,
    const float* __restrict__ gat_w, const float* __restrict__ att_src,
    const float* __restrict__ att_dst, const int* __restrict__ src,
    const int* __restrict__ dst, ushort* __restrict__ Wt,
    float* __restrict__ bp, unsigned int* __restrict__ tmp, int* __restrict__ tab)
{
    __shared__ __align__(16) char smem[18560];
    int blk = blockIdx.x;
    int t = threadIdx.x;

    if (blk < 16) {
        float* Wl = (float*)smem;            // 32*129 floats
        float* aak = Wl + PW_KCH * 129;
        int layer = blk >> 2;
        int k0 = (blk & 3) * PW_KCH;
        const float* bn; const float* W;
        if (layer == 0) { bn = bn_feat; W = w_feat; }
        else { bn = bns_conv + (layer - 1) * 4 * HIDD; W = gat_w + (size_t)(layer - 1) * HIDD * HIDD; }
        if (t < PW_KCH) {
            int k = k0 + t;
            aak[t] = bn[k] * rsqrtf(bn[3 * HIDD + k] + EPSS);
        }
        for (int i = t; i < PW_KCH * 128; i += 256) {
            int kk = i >> 7, n = i & 127;
            Wl[kk * 129 + n] = W[(size_t)(k0 + kk) * 128 + n];
        }
        __syncthreads();
        ushort* wrow = Wt + (size_t)layer * WSTRIDE;
        for (int i = t; i < 128 * PW_KCH; i += 256) {
            int n = i >> 5, kk = i & 31;
            wrow[n * 128 + k0 + kk] = f2bf(aak[kk] * Wl[kk * 129 + n]);
        }
    } else if (blk < 20) {
        float* ccs = (float*)smem;
        int layer = blk - 16;
        const float* bn; const float* W;
        if (layer == 0) { bn = bn_feat; W = w_feat; }
        else { bn = bns_conv + (layer - 1) * 4 * HIDD; W = gat_w + (size_t)(layer - 1) * HIDD * HIDD; }
        if (t < 128) {
            float a = bn[t] * rsqrtf(bn[3 * HIDD + t] + EPSS);
            ccs[t] = bn[HIDD + t] - bn[2 * HIDD + t] * a;
        }
        __syncthreads();
        if (t < 128) {
            float bacc = (layer == 0) ? b_feat[t] : 0.f;
            for (int k = 0; k < 128; ++k) bacc += ccs[k] * W[(size_t)k * 128 + t];
            bp[layer * BSTRIDE + t] = bacc;
        }
    } else if (blk < 23) {
        float* Wl   = (float*)smem;               // 32*129 floats (16512 B)
        float* redS = (float*)(smem + 16512);     // 256 floats
        float* redD = redS + 256;
        int li = blk - 20;
        int L = li + 1;
        const float* bn = bns_conv + li * 4 * HIDD;
        const float* W  = gat_w + (size_t)li * HIDD * HIDD;
        const float* as = att_src + li * HEADS * CDIM;
        const float* ad = att_dst + li * HEADS * CDIM;
        ushort* Wo = Wt + (size_t)L * WSTRIDE;
        int kl = t >> 3, h = t & 7;
        float acc_s = 0.f, acc_d = 0.f;
        for (int c0 = 0; c0 < 4; ++c0) {
            int k0 = c0 * 32;
            __syncthreads();
            for (int i = t; i < 32 * 128; i += 256) {
                int kk = i >> 7, n = i & 127;
                Wl[kk * 129 + n] = W[(size_t)(k0 + kk) * 128 + n];
            }
            __syncthreads();
            int k = k0 + kl;
            float a  = bn[k] * rsqrtf(bn[3 * HIDD + k] + EPSS);
            float cc = bn[HIDD + k] - bn[2 * HIDD + k] * a;
            float ps = 0.f, pd = 0.f;
            #pragma unroll
            for (int c = 0; c < 16; ++c) {
                float wv = Wl[kl * 129 + h * 16 + c];
                ps += wv * as[h * 16 + c];
                pd += wv * ad[h * 16 + c];
            }
            Wo[(128 + h) * 128 + k] = f2bf(a * ps);
            Wo[(136 + h) * 128 + k] = f2bf(a * pd);
            acc_s += cc * ps;
            acc_d += cc * pd;
        }
        redS[t] = acc_s; redD[t] = acc_d;
        __syncthreads();
        if (t < 8) {
            float s = 0.f, d = 0.f;
            for (int q = 0; q < 32; ++q) { s += redS[q * 8 + t]; d += redD[q * 8 + t]; }
            bp[L * BSTRIDE + 128 + t] = s;
            bp[L * BSTRIDE + 136 + t] = d;
        }
    } else {
        // ---- bin block k
        unsigned int* stage = (unsigned int*)smem;        // 3125 entries (12500 B)
        int* hist = (int*)(smem + 12512);                 // 392 ints
        int* A    = hist + TABW;                          // 512 ints (scan)
        int k = blk - 23;
        int cbeg = k * BIN_CHUNK;
        int cend = cbeg + BIN_CHUNK;

        for (int i = t; i < TABW; i += 256) hist[i] = 0;
        __syncthreads();
        for (int e = cbeg + t; e < cend; e += 256)
            atomicAdd(&hist[dst[e] >> BSH], 1);
        __syncthreads();
        // inclusive scan over 512 slots (391 real) with 256 threads, in-place
        int i1 = t + 256;
        int c0 = hist[t];
        int c1 = (i1 < TABW) ? hist[i1] : 0;
        A[t] = c0; A[i1] = c1;
        __syncthreads();
        for (int d = 1; d < 512; d <<= 1) {
            int a0 = (t >= d) ? A[t - d] : 0;
            int a1 = A[i1 - d];           // i1 >= 256 > d always valid
            __syncthreads();
            A[t] += a0; A[i1] += a1;
            __syncthreads();
        }
        // excl offsets -> table + cursors
        int e0 = A[t] - c0;
        int e1 = A[i1] - c1;
        tab[(size_t)k * TABW + t] = e0;
        if (i1 < TABW) tab[(size_t)k * TABW + i1] = e1;
        hist[t] = e0;
        if (i1 < TABW) hist[i1] = e1;
        __syncthreads();
        // scatter (re-read edges; L2-hot) into LDS stage at bucket offsets
        for (int e = cbeg + t; e < cend; e += 256) {
            int d = dst[e];
            int b = d >> BSH;
            unsigned int pk = ((unsigned int)(d & (BSZ - 1)) << 16) | (unsigned int)src[e];
            int p = atomicAdd(&hist[b], 1);
            stage[p] = pk;
        }
        __syncthreads();
        // coalesced dump to private region
        for (int i = t; i < BIN_CHUNK; i += 256)
            tmp[(size_t)k * BIN_CHUNK + i] = stage[i];
    }
}

// ================================================================ kernel B: sort (391) + GEMM layer0 (391)
// sort block b: gather its bucket's segments from all 256 bin regions via tab,
// counting-sort by local dst into fixed csr region b*CAPB, 8-padded rows.
// rowptr[node] = (b*CAPB + off) | deg<<21   (max base 1.8M < 2^21)
__global__ __launch_bounds__(256) void sort_gemm0(
    const int* __restrict__ tab, const unsigned int* __restrict__ tmp,
    ushort* __restrict__ csr, unsigned int* __restrict__ rowptr,
    const float* __restrict__ x, const ushort* __restrict__ Wt,
    const float* __restrict__ bp, ushort* __restrict__ h_a)
{
    int t = threadIdx.x;
    if (blockIdx.x < NB) {
        __shared__ unsigned int buf[SORT_BUF];   // 18432 B
        __shared__ int sc[256];
        __shared__ int o0s[256];
        __shared__ int hist[BSZ], pex[BSZ], cur[BSZ];
        int b = blockIdx.x;
        int base_out = b * CAPB;

        int o0 = tab[(size_t)t * TABW + b];
        int o1 = tab[(size_t)t * TABW + b + 1];
        int c = o1 - o0;
        o0s[t] = o0;
        sc[t] = c;
        __syncthreads();
        for (int d = 1; d < 256; d <<= 1) {
            int a = (t >= d) ? sc[t - d] : 0;
            __syncthreads();
            sc[t] += a;
            __syncthreads();
        }
        int m = sc[255];
        int mybase = sc[t] - c;
        if (m > CAPB - BSZ * 7) m = CAPB - BSZ * 7;   // statistically impossible clamp
        // copy this thread's segment (bin block t) into buf
        for (int j = 0; j < c; ++j) {
            int p = mybase + j;
            if (p < m) buf[p] = tmp[(size_t)t * BIN_CHUNK + o0s[t] + j];
        }
        if (t < BSZ) hist[t] = 0;
        __syncthreads();
        for (int i = t; i < m; i += 256) atomicAdd(&hist[buf[i] >> 16], 1);
        __syncthreads();
        int pd = 0;
        if (t < BSZ) { pd = (hist[t] + 7) & ~7; pex[t] = pd; }
        __syncthreads();
        for (int d = 1; d < BSZ; d <<= 1) {
            int a = (t < BSZ && t >= d) ? pex[t - d] : 0;
            __syncthreads();
            if (t < BSZ) pex[t] += a;
            __syncthreads();
        }
        if (t < BSZ) {
            int ex = pex[t] - pd;
            pex[t] = ex;
            cur[t] = ex;
            int node = b * BSZ + t;
            if (node < NN)
                rowptr[node] = (unsigned int)(base_out + ex) | ((unsigned int)hist[t] << 21);
        }
        __syncthreads();
        for (int i = t; i < m; i += 256) {
            unsigned int pk = buf[i];
            int dl = pk >> 16;
            int p = atomicAdd(&cur[dl], 1);
            csr[base_out + p] = (ushort)(pk & 0xffffu);
        }
        __syncthreads();
        if (t < BSZ) {
            int ex = pex[t], hn = hist[t], pdn = (hn + 7) & ~7;
            for (int i = hn; i < pdn; ++i) csr[base_out + ex + i] = 0;
        }
    } else {
        // GEMM layer 0: h_a = relu(bn(x) @ w_feat + b_feat)
        gemm_core<1, 0>(blockIdx.x - NB, t, x, Wt, bp, h_a,
                        nullptr, nullptr, nullptr, NN, 1);
    }
}

// ================================================================ standalone conv GEMM (layers 1-3)
__global__ __launch_bounds__(256) void gemm_conv(const ushort* __restrict__ Ain,
    const ushort* __restrict__ Wt, const float* __restrict__ bias,
    ushort* __restrict__ Out, unsigned char* __restrict__ h8,
    float* __restrict__ alph_s, float* __restrict__ alph_d)
{
    gemm_core<0, 1>(blockIdx.x, threadIdx.x, Ain, Wt, bias, Out, h8,
                    alph_s, alph_d, NN, 0);
}

// ================================================================ GAT aggregation (R12-proven)
__global__ __launch_bounds__(256) void gat_aggregate(
    const ushort* __restrict__ h, const unsigned char* __restrict__ h8,
    const float* __restrict__ as, const float* __restrict__ ad,
    const unsigned int* __restrict__ rowptr, const ushort* __restrict__ csr,
    const float* __restrict__ bias, ushort* __restrict__ out)
{
    int wid = (blockIdx.x * 256 + threadIdx.x) >> 6;
    int v = __builtin_amdgcn_readfirstlane(wid);
    if (v >= NN) return;
    int lane = threadIdx.x & 63;
    int hd = lane >> 3;
    int slot = lane & 7;
    int gbase = lane & ~7;
    unsigned int rp = rowptr[v];
    int beg = rp & 0x1FFFFF;
    int cnt = rp >> 21;
    float adv = ad[v * HEADS + hd];

    const unsigned int* h32 = (const unsigned int*)h;
    const ushort* h8v = (const ushort*)h8;      // 2 fp8 channels per lane

    float wself = __expf(lrelu(as[v * HEADS + hd] + adv));
    unsigned int hv = h32[(size_t)v * 64 + lane];
    float acc0 = wself * bf2f((ushort)(hv & 0xffff));
    float acc1 = wself * bf2f((ushort)(hv >> 16));
    float wsum_own = 0.f;

    int ngro = (cnt + 7) >> 3;
    if (ngro > 0) {
        const uint4* epk = (const uint4*)(csr + beg);
        int u0[8], u1[8];
        float l_own0, l_own1;
        unsigned int x0[8], x1[8];
        {
            uint4 pk = epk[0];
            u0[0] = pk.x & 0xffff; u0[1] = pk.x >> 16;
            u0[2] = pk.y & 0xffff; u0[3] = pk.y >> 16;
            u0[4] = pk.z & 0xffff; u0[5] = pk.z >> 16;
            u0[6] = pk.w & 0xffff; u0[7] = pk.w >> 16;
            unsigned int d = slot < 4 ? (slot < 2 ? pk.x : pk.y)
                                      : (slot < 6 ? pk.z : pk.w);
            int u_own = (slot & 1) ? (int)(d >> 16) : (int)(d & 0xffff);
            l_own0 = as[u_own * HEADS + hd];
            #pragma unroll
            for (int j = 0; j < 8; ++j) x0[j] = h8v[(size_t)u0[j] * 64 + lane];
        }
        for (int g = 0; g < ngro; ++g) {
            bool more = (g + 1 < ngro);
            if (more) {
                uint4 pk = epk[g + 1];
                u1[0] = pk.x & 0xffff; u1[1] = pk.x >> 16;
                u1[2] = pk.y & 0xffff; u1[3] = pk.y >> 16;
                u1[4] = pk.z & 0xffff; u1[5] = pk.z >> 16;
                u1[6] = pk.w & 0xffff; u1[7] = pk.w >> 16;
                unsigned int d = slot < 4 ? (slot < 2 ? pk.x : pk.y)
                                          : (slot < 6 ? pk.z : pk.w);
                int u_own = (slot & 1) ? (int)(d >> 16) : (int)(d & 0xffff);
                l_own1 = as[u_own * HEADS + hd];
                #pragma unroll
                for (int j = 0; j < 8; ++j) x1[j] = h8v[(size_t)u1[j] * 64 + lane];
            }
            float w_own = __expf(lrelu(l_own0 + adv));
            if (g * 8 + slot >= cnt) w_own = 0.f;
            wsum_own += w_own;
            #pragma unroll
            for (int j = 0; j < 8; ++j) {
                float wj = __shfl(w_own, gbase + j, 64);
                f32x2 hv2 = __builtin_amdgcn_cvt_pk_f32_fp8((int)x0[j], false);
                acc0 += wj * hv2[0];
                acc1 += wj * hv2[1];
            }
            if (more) {
                l_own0 = l_own1;
                #pragma unroll
                for (int j = 0; j < 8; ++j) { u0[j] = u1[j]; x0[j] = x1[j]; }
            }
        }
    }

    #pragma unroll
    for (int off = 1; off < 8; off <<= 1) wsum_own += __shfl_xor(wsum_own, off);
    float denom = wself + wsum_own;

    float inv = 1.f / (denom + 1e-16f);
    int c = 2 * lane;
    float o0 = fmaxf(acc0 * inv + bias[c], 0.f);
    float o1 = fmaxf(acc1 * inv + bias[c + 1], 0.f);
    ((unsigned int*)out)[(size_t)v * 64 + lane] =
        (unsigned int)f2bf(o0) | ((unsigned int)f2bf(o1) << 16);
}

// ================================================================ pool + FC head (R6-proven fused)
__global__ __launch_bounds__(256) void pool_head(const ushort* __restrict__ h,
    const int* __restrict__ batch,
    const float* __restrict__ bns_fc, const float* __restrict__ fc_w,
    const float* __restrict__ fc_b, const float* __restrict__ bn_hid,
    const float* __restrict__ w_class, const float* __restrict__ b_class,
    float* __restrict__ out)
{
    __shared__ float sred[256];
    __shared__ float v1[HIDD];
    __shared__ float v2[HIDD];
    __shared__ float lg[NCLS];
    __shared__ float lse;
    __shared__ int bounds[2];
    int gb = blockIdx.x, t = threadIdx.x;

    if (t < 2) {
        int key = gb + t;
        int lo = 0, hi = NN;
        while (lo < hi) {
            int mid = (lo + hi) >> 1;
            if (batch[mid] < key) lo = mid + 1; else hi = mid;
        }
        bounds[t] = lo;
    }
    __syncthreads();
    int beg = bounds[0], end = bounds[1];

    int half = t >> 7, c = t & 127;
    float a0 = 0.f, a1 = 0.f, a2 = 0.f, a3 = 0.f;
    int r = beg + half;
    for (; r + 6 < end; r += 8) {
        a0 += bf2f(h[(size_t)r * HIDD + c]);
        a1 += bf2f(h[(size_t)(r + 2) * HIDD + c]);
        a2 += bf2f(h[(size_t)(r + 4) * HIDD + c]);
        a3 += bf2f(h[(size_t)(r + 6) * HIDD + c]);
    }
    for (; r < end; r += 2) a0 += bf2f(h[(size_t)r * HIDD + c]);
    sred[t] = (a0 + a1) + (a2 + a3);
    __syncthreads();

    if (t < HIDD) {
        float gv = sred[t] + sred[t + 128];
        float gamma = bns_fc[t], beta = bns_fc[HIDD + t];
        float mu = bns_fc[2 * HIDD + t], var = bns_fc[3 * HIDD + t];
        v1[t] = (gv - mu) * gamma * rsqrtf(var + EPSS) + beta;
    }
    __syncthreads();

    if (t < HIDD) {
        float acc = fc_b[t];
        for (int k = 0; k < HIDD; ++k) acc += v1[k] * fc_w[k * HIDD + t];
        acc = fmaxf(acc, 0.f);
        float gamma = bn_hid[t], beta = bn_hid[HIDD + t];
        float mu = bn_hid[2 * HIDD + t], var = bn_hid[3 * HIDD + t];
        v2[t] = (acc - mu) * gamma * rsqrtf(var + EPSS) + beta;
    }
    __syncthreads();

    if (t < NCLS) {
        float acc2 = b_class[t];
        for (int k = 0; k < HIDD; ++k) acc2 += v2[k] * w_class[k * NCLS + t];
        lg[t] = acc2;
    }
    __syncthreads();
    if (t == 0) {
        float mx = lg[0];
        for (int i = 1; i < NCLS; ++i) mx = fmaxf(mx, lg[i]);
        float ss = 0.f;
        for (int i = 0; i < NCLS; ++i) ss += __expf(lg[i] - mx);
        lse = mx + __logf(ss);
    }
    __syncthreads();
    if (t < NCLS) out[gb * NCLS + t] = lg[t] - lse;
}

// ================================================================ launch (9 dispatches)
extern "C" void kernel_launch(void* const* d_in, const int* in_sizes, int n_in,
                              void* d_out, int out_size, void* d_ws, size_t ws_size,
                              hipStream_t stream)
{
    const float* x        = (const float*)d_in[0];
    const int*   edge     = (const int*)d_in[1];
    const int*   batch    = (const int*)d_in[2];
    const float* bn_feat  = (const float*)d_in[3];
    const float* w_feat   = (const float*)d_in[4];
    const float* b_feat   = (const float*)d_in[5];
    const float* bns_conv = (const float*)d_in[6];
    const float* gat_w    = (const float*)d_in[7];
    const float* att_src  = (const float*)d_in[8];
    const float* att_dst  = (const float*)d_in[9];
    const float* gat_b    = (const float*)d_in[10];
    const float* bns_fc   = (const float*)d_in[11];
    const float* fc_w     = (const float*)d_in[12];
    const float* fc_b     = (const float*)d_in[13];
    const float* bn_hid   = (const float*)d_in[14];
    const float* w_class  = (const float*)d_in[15];
    const float* b_class  = (const float*)d_in[16];
    float* out = (float*)d_out;
    (void)in_sizes; (void)n_in; (void)out_size; (void)ws_size;

    char* ws = (char*)d_ws;
    size_t off = 0;
    auto alloc = [&](size_t bytes) {
        void* p = ws + off;
        off = (off + bytes + 255) & ~(size_t)255;
        return p;
    };
    ushort* Wt        = (ushort*)alloc((size_t)4 * WSTRIDE * sizeof(ushort));
    float*  bp        = (float*)alloc(4 * BSTRIDE * sizeof(float));
    ushort* h_a       = (ushort*)alloc((size_t)NN * HIDD * sizeof(ushort));
    ushort* h_b       = (ushort*)alloc((size_t)NN * HIDD * sizeof(ushort));
    unsigned char* h8 = (unsigned char*)alloc((size_t)NN * HIDD);
    float*  alph_s    = (float*)alloc((size_t)NN * HEADS * sizeof(float));
    float*  alph_d    = (float*)alloc((size_t)NN * HEADS * sizeof(float));
    int*    tab       = (int*)alloc((size_t)BIN_BLOCKS * TABW * sizeof(int));
    unsigned int* tmp = (unsigned int*)alloc((size_t)E_EDGES * sizeof(unsigned int));
    unsigned int* rowptr = (unsigned int*)alloc((size_t)NN * sizeof(unsigned int));
    ushort* csr       = (ushort*)alloc((size_t)NB * CAPB * sizeof(ushort) + 64);

    const int* src = edge;
    const int* dst = edge + E_EDGES;

    prep_bin<<<279, 256, 0, stream>>>(bn_feat, w_feat, b_feat, bns_conv, gat_w,
                                      att_src, att_dst, src, dst, Wt, bp, tmp, tab);
    sort_gemm0<<<NB + GTILES, 256, 0, stream>>>(tab, tmp, csr, rowptr,
                                                x, Wt, bp, h_a);

    for (int i = 0; i < NCONV; ++i) {
        gemm_conv<<<GTILES, 256, 0, stream>>>(h_a,
            Wt + (size_t)(i + 1) * WSTRIDE, bp + (i + 1) * BSTRIDE, h_b, h8,
            alph_s, alph_d);
        gat_aggregate<<<(NN + 3) / 4, 256, 0, stream>>>(h_b, h8, alph_s, alph_d,
                                                        rowptr, csr, gat_b + i * HIDD, h_a);
    }

    pool_head<<<NGG, 256, 0, stream>>>(h_a, batch, bns_fc, fc_w, fc_b, bn_hid,
                                       w_class, b_class, out);
}

// Round 15
// 317.433 us; speedup vs baseline: 1.6176x; 1.0269x over previous
//
#include <hip/hip_runtime.h>

#define NN 50000
#define E_EDGES 800000
#define F_INN 128
#define HIDD 128
#define HEADS 8
#define CDIM 16
#define NCLS 10
#define NGG 64
#define NCONV 3
#define EPSS 1e-5f
#define NEG_SLOPE 0.2f

// Wt layout: per layer 144 rows (output cols) x 128 k, bf16.
#define WROWS 144
#define WSTRIDE (WROWS * 128)
#define BSTRIDE 144

// bucket partition: 128 dst nodes per bucket
#define BSH 7
#define BSZ 128
#define NB ((NN + BSZ - 1) / BSZ)   // 391
#define BIN_BLOCKS 256
#define BIN_CHUNK (E_EDGES / BIN_BLOCKS)   // 3125 exact
#define TABW 392                     // 391 offsets + sentinel
#define CAPB 4608                    // fixed csr region/bucket
#define SORT_BUF 4608
#define PW_KCH 32
#define GTILES ((NN + 127) / 128)    // 391 gemm blocks (128 rows each)

typedef __attribute__((ext_vector_type(8))) short short8;
typedef __attribute__((ext_vector_type(4))) float f32x4;
typedef __attribute__((ext_vector_type(2))) float f32x2;

__device__ __forceinline__ float lrelu(float x) { return x > 0.f ? x : NEG_SLOPE * x; }

__device__ __forceinline__ float bf2f(ushort u) {
    union { unsigned int i; float f; } v;
    v.i = ((unsigned int)u) << 16;
    return v.f;
}
__device__ __forceinline__ ushort f2bf(float f) {
    union { float f; unsigned int i; } v;
    v.f = f;
    unsigned int r = (v.i + 0x7fffu + ((v.i >> 16) & 1u)) >> 16;  // RNE
    return (ushort)r;
}
// OCP e4m3 encode via HW pack (saturating); take byte 0
__device__ __forceinline__ unsigned char f2fp8(float f) {
    int r = __builtin_amdgcn_cvt_pk_fp8_f32(f, f, 0, false);
    return (unsigned char)(r & 0xff);
}

// ================================================================ GEMM core (device fn)
// ALPHAS=0: Out (bf16) + relu (layer 0).
// ALPHAS=1: conv layer — h8 (fp8) + alpha projections ONLY; h_b bf16 is DEAD
//           (aggregate self-loop now reads fp8 too) -> 12.8MB fewer stores/layer.
template <int F32IN, int ALPHAS>
__device__ __forceinline__ void gemm_core(int tile, int t,
    const void* __restrict__ Ain, const ushort* __restrict__ Wt,
    const float* __restrict__ bias, ushort* __restrict__ Out,
    unsigned char* __restrict__ h8, float* __restrict__ alph_s,
    float* __restrict__ alph_d, int n, int dorelu)
{
    const int NT = ALPHAS ? 9 : 8;
    int wave = t >> 6, lane = t & 63;
    int m16 = lane & 15, quad = lane >> 4;
    int rbase = tile * 128 + wave * 32;

    short8 afrag[2][4];
    #pragma unroll
    for (int tt = 0; tt < 2; ++tt) {
        int arow_i = rbase + tt * 16 + m16;
        size_t arow = (size_t)(arow_i < n ? arow_i : 0) * HIDD + quad * 8;
        if (F32IN) {
            const float* ap = (const float*)Ain + arow;
            #pragma unroll
            for (int kk = 0; kk < 4; ++kk) {
                float4 lo = *(const float4*)(ap + kk * 32);
                float4 hi = *(const float4*)(ap + kk * 32 + 4);
                short8 f;
                f[0] = (short)f2bf(lo.x); f[1] = (short)f2bf(lo.y);
                f[2] = (short)f2bf(lo.z); f[3] = (short)f2bf(lo.w);
                f[4] = (short)f2bf(hi.x); f[5] = (short)f2bf(hi.y);
                f[6] = (short)f2bf(hi.z); f[7] = (short)f2bf(hi.w);
                afrag[tt][kk] = f;
            }
        } else {
            const ushort* ap = (const ushort*)Ain + arow;
            #pragma unroll
            for (int kk = 0; kk < 4; ++kk)
                afrag[tt][kk] = *(const short8*)(ap + kk * 32);
        }
    }

    f32x4 acc[2][9];
    #pragma unroll
    for (int tt = 0; tt < 2; ++tt)
        #pragma unroll
        for (int nt = 0; nt < NT; ++nt) acc[tt][nt] = (f32x4){0.f, 0.f, 0.f, 0.f};

    #pragma unroll
    for (int nt = 0; nt < NT; ++nt) {
        const ushort* brow = Wt + (size_t)(nt * 16 + m16) * HIDD + quad * 8;
        #pragma unroll
        for (int kk = 0; kk < 4; ++kk) {
            short8 bfrag = *(const short8*)(brow + kk * 32);
            acc[0][nt] = __builtin_amdgcn_mfma_f32_16x16x32_bf16(afrag[0][kk], bfrag, acc[0][nt], 0, 0, 0);
            acc[1][nt] = __builtin_amdgcn_mfma_f32_16x16x32_bf16(afrag[1][kk], bfrag, acc[1][nt], 0, 0, 0);
        }
    }

    #pragma unroll
    for (int tt = 0; tt < 2; ++tt) {
        int tb = rbase + tt * 16;
        #pragma unroll
        for (int nt = 0; nt < 8; ++nt) {
            int col = nt * 16 + m16;
            float bv = bias[col];
            #pragma unroll
            for (int r = 0; r < 4; ++r) {
                int orow = tb + quad * 4 + r;
                if (orow < n) {
                    float v = acc[tt][nt][r] + bv;
                    if (ALPHAS) {
                        h8[(size_t)orow * HIDD + col] = f2fp8(v);
                    } else {
                        if (dorelu) v = fmaxf(v, 0.f);
                        Out[(size_t)orow * HIDD + col] = f2bf(v);
                    }
                }
            }
        }
        if (ALPHAS) {
            float bv = bias[128 + m16];
            #pragma unroll
            for (int r = 0; r < 4; ++r) {
                int orow = tb + quad * 4 + r;
                if (orow < n) {
                    float v = acc[tt][8][r] + bv;
                    if (m16 < 8) alph_s[orow * HEADS + m16] = v;
                    else         alph_d[orow * HEADS + (m16 - 8)] = v;
                }
            }
        }
    }
}

// ================================================================ kernel A: prep + bin (R14-proven)
__global__ __launch_bounds__(256) void prep_bin(
    const float* __restrict__ bn_feat, const float* __restrict__ w_feat,
    const float* __restrict__ b_feat, const float* __restrict__ bns_conv,
    const float* __restrict__ gat_w, const float* __restrict__ att_src,
    const float* __restrict__ att_dst, const int* __restrict__ src,
    const int* __restrict__ dst, ushort* __restrict__ Wt,
    float* __restrict__ bp, unsigned int* __restrict__ tmp, int* __restrict__ tab)
{
    __shared__ __align__(16) char smem[18560];
    int blk = blockIdx.x;
    int t = threadIdx.x;

    if (blk < 16) {
        float* Wl = (float*)smem;            // 32*129 floats
        float* aak = Wl + PW_KCH * 129;
        int layer = blk >> 2;
        int k0 = (blk & 3) * PW_KCH;
        const float* bn; const float* W;
        if (layer == 0) { bn = bn_feat; W = w_feat; }
        else { bn = bns_conv + (layer - 1) * 4 * HIDD; W = gat_w + (size_t)(layer - 1) * HIDD * HIDD; }
        if (t < PW_KCH) {
            int k = k0 + t;
            aak[t] = bn[k] * rsqrtf(bn[3 * HIDD + k] + EPSS);
        }
        for (int i = t; i < PW_KCH * 128; i += 256) {
            int kk = i >> 7, n = i & 127;
            Wl[kk * 129 + n] = W[(size_t)(k0 + kk) * 128 + n];
        }
        __syncthreads();
        ushort* wrow = Wt + (size_t)layer * WSTRIDE;
        for (int i = t; i < 128 * PW_KCH; i += 256) {
            int n = i >> 5, kk = i & 31;
            wrow[n * 128 + k0 + kk] = f2bf(aak[kk] * Wl[kk * 129 + n]);
        }
    } else if (blk < 20) {
        float* ccs = (float*)smem;
        int layer = blk - 16;
        const float* bn; const float* W;
        if (layer == 0) { bn = bn_feat; W = w_feat; }
        else { bn = bns_conv + (layer - 1) * 4 * HIDD; W = gat_w + (size_t)(layer - 1) * HIDD * HIDD; }
        if (t < 128) {
            float a = bn[t] * rsqrtf(bn[3 * HIDD + t] + EPSS);
            ccs[t] = bn[HIDD + t] - bn[2 * HIDD + t] * a;
        }
        __syncthreads();
        if (t < 128) {
            float bacc = (layer == 0) ? b_feat[t] : 0.f;
            for (int k = 0; k < 128; ++k) bacc += ccs[k] * W[(size_t)k * 128 + t];
            bp[layer * BSTRIDE + t] = bacc;
        }
    } else if (blk < 23) {
        float* Wl   = (float*)smem;               // 32*129 floats (16512 B)
        float* redS = (float*)(smem + 16512);     // 256 floats
        float* redD = redS + 256;
        int li = blk - 20;
        int L = li + 1;
        const float* bn = bns_conv + li * 4 * HIDD;
        const float* W  = gat_w + (size_t)li * HIDD * HIDD;
        const float* as = att_src + li * HEADS * CDIM;
        const float* ad = att_dst + li * HEADS * CDIM;
        ushort* Wo = Wt + (size_t)L * WSTRIDE;
        int kl = t >> 3, h = t & 7;
        float acc_s = 0.f, acc_d = 0.f;
        for (int c0 = 0; c0 < 4; ++c0) {
            int k0 = c0 * 32;
            __syncthreads();
            for (int i = t; i < 32 * 128; i += 256) {
                int kk = i >> 7, n = i & 127;
                Wl[kk * 129 + n] = W[(size_t)(k0 + kk) * 128 + n];
            }
            __syncthreads();
            int k = k0 + kl;
            float a  = bn[k] * rsqrtf(bn[3 * HIDD + k] + EPSS);
            float cc = bn[HIDD + k] - bn[2 * HIDD + k] * a;
            float ps = 0.f, pd = 0.f;
            #pragma unroll
            for (int c = 0; c < 16; ++c) {
                float wv = Wl[kl * 129 + h * 16 + c];
                ps += wv * as[h * 16 + c];
                pd += wv * ad[h * 16 + c];
            }
            Wo[(128 + h) * 128 + k] = f2bf(a * ps);
            Wo[(136 + h) * 128 + k] = f2bf(a * pd);
            acc_s += cc * ps;
            acc_d += cc * pd;
        }
        redS[t] = acc_s; redD[t] = acc_d;
        __syncthreads();
        if (t < 8) {
            float s = 0.f, d = 0.f;
            for (int q = 0; q < 32; ++q) { s += redS[q * 8 + t]; d += redD[q * 8 + t]; }
            bp[L * BSTRIDE + 128 + t] = s;
            bp[L * BSTRIDE + 136 + t] = d;
        }
    } else {
        unsigned int* stage = (unsigned int*)smem;        // 3125 entries (12500 B)
        int* hist = (int*)(smem + 12512);                 // 392 ints
        int* A    = hist + TABW;                          // 512 ints (scan)
        int k = blk - 23;
        int cbeg = k * BIN_CHUNK;
        int cend = cbeg + BIN_CHUNK;

        for (int i = t; i < TABW; i += 256) hist[i] = 0;
        __syncthreads();
        for (int e = cbeg + t; e < cend; e += 256)
            atomicAdd(&hist[dst[e] >> BSH], 1);
        __syncthreads();
        int i1 = t + 256;
        int c0 = hist[t];
        int c1 = (i1 < TABW) ? hist[i1] : 0;
        A[t] = c0; A[i1] = c1;
        __syncthreads();
        for (int d = 1; d < 512; d <<= 1) {
            int a0 = (t >= d) ? A[t - d] : 0;
            int a1 = A[i1 - d];
            __syncthreads();
            A[t] += a0; A[i1] += a1;
            __syncthreads();
        }
        int e0 = A[t] - c0;
        int e1 = A[i1] - c1;
        tab[(size_t)k * TABW + t] = e0;
        if (i1 < TABW) tab[(size_t)k * TABW + i1] = e1;
        hist[t] = e0;
        if (i1 < TABW) hist[i1] = e1;
        __syncthreads();
        for (int e = cbeg + t; e < cend; e += 256) {
            int d = dst[e];
            int b = d >> BSH;
            unsigned int pk = ((unsigned int)(d & (BSZ - 1)) << 16) | (unsigned int)src[e];
            int p = atomicAdd(&hist[b], 1);
            stage[p] = pk;
        }
        __syncthreads();
        for (int i = t; i < BIN_CHUNK; i += 256)
            tmp[(size_t)k * BIN_CHUNK + i] = stage[i];
    }
}

// ================================================================ kernel B: sort (391) + GEMM layer0 (391)  [R14-proven]
__global__ __launch_bounds__(256) void sort_gemm0(
    const int* __restrict__ tab, const unsigned int* __restrict__ tmp,
    ushort* __restrict__ csr, unsigned int* __restrict__ rowptr,
    const float* __restrict__ x, const ushort* __restrict__ Wt,
    const float* __restrict__ bp, ushort* __restrict__ h_a)
{
    int t = threadIdx.x;
    if (blockIdx.x < NB) {
        __shared__ unsigned int buf[SORT_BUF];   // 18432 B
        __shared__ int sc[256];
        __shared__ int o0s[256];
        __shared__ int hist[BSZ], pex[BSZ], cur[BSZ];
        int b = blockIdx.x;
        int base_out = b * CAPB;

        int o0 = tab[(size_t)t * TABW + b];
        int o1 = tab[(size_t)t * TABW + b + 1];
        int c = o1 - o0;
        o0s[t] = o0;
        sc[t] = c;
        __syncthreads();
        for (int d = 1; d < 256; d <<= 1) {
            int a = (t >= d) ? sc[t - d] : 0;
            __syncthreads();
            sc[t] += a;
            __syncthreads();
        }
        int m = sc[255];
        int mybase = sc[t] - c;
        if (m > CAPB - BSZ * 7) m = CAPB - BSZ * 7;
        for (int j = 0; j < c; ++j) {
            int p = mybase + j;
            if (p < m) buf[p] = tmp[(size_t)t * BIN_CHUNK + o0s[t] + j];
        }
        if (t < BSZ) hist[t] = 0;
        __syncthreads();
        for (int i = t; i < m; i += 256) atomicAdd(&hist[buf[i] >> 16], 1);
        __syncthreads();
        int pd = 0;
        if (t < BSZ) { pd = (hist[t] + 7) & ~7; pex[t] = pd; }
        __syncthreads();
        for (int d = 1; d < BSZ; d <<= 1) {
            int a = (t < BSZ && t >= d) ? pex[t - d] : 0;
            __syncthreads();
            if (t < BSZ) pex[t] += a;
            __syncthreads();
        }
        if (t < BSZ) {
            int ex = pex[t] - pd;
            pex[t] = ex;
            cur[t] = ex;
            int node = b * BSZ + t;
            if (node < NN)
                rowptr[node] = (unsigned int)(base_out + ex) | ((unsigned int)hist[t] << 21);
        }
        __syncthreads();
        for (int i = t; i < m; i += 256) {
            unsigned int pk = buf[i];
            int dl = pk >> 16;
            int p = atomicAdd(&cur[dl], 1);
            csr[base_out + p] = (ushort)(pk & 0xffffu);
        }
        __syncthreads();
        if (t < BSZ) {
            int ex = pex[t], hn = hist[t], pdn = (hn + 7) & ~7;
            for (int i = hn; i < pdn; ++i) csr[base_out + ex + i] = 0;
        }
    } else {
        gemm_core<1, 0>(blockIdx.x - NB, t, x, Wt, bp, h_a,
                        nullptr, nullptr, nullptr, NN, 1);
    }
}

// ================================================================ conv GEMM (layers 1-3): fp8 + alphas only
__global__ __launch_bounds__(256) void gemm_conv(const ushort* __restrict__ Ain,
    const ushort* __restrict__ Wt, const float* __restrict__ bias,
    unsigned char* __restrict__ h8, float* __restrict__ alph_s,
    float* __restrict__ alph_d)
{
    gemm_core<0, 1>(blockIdx.x, threadIdx.x, Ain, Wt, bias, nullptr, h8,
                    alph_s, alph_d, NN, 0);
}

// ================================================================ GAT aggregation
// Self-loop now reads fp8 too (h_b dead): all inputs via h8, 128B/row.
__global__ __launch_bounds__(256) void gat_aggregate(
    const unsigned char* __restrict__ h8,
    const float* __restrict__ as, const float* __restrict__ ad,
    const unsigned int* __restrict__ rowptr, const ushort* __restrict__ csr,
    const float* __restrict__ bias, ushort* __restrict__ out)
{
    int wid = (blockIdx.x * 256 + threadIdx.x) >> 6;
    int v = __builtin_amdgcn_readfirstlane(wid);
    if (v >= NN) return;
    int lane = threadIdx.x & 63;
    int hd = lane >> 3;
    int slot = lane & 7;
    int gbase = lane & ~7;
    unsigned int rp = rowptr[v];
    int beg = rp & 0x1FFFFF;
    int cnt = rp >> 21;
    float adv = ad[v * HEADS + hd];

    const ushort* h8v = (const ushort*)h8;      // 2 fp8 channels per lane

    float wself = __expf(lrelu(as[v * HEADS + hd] + adv));
    f32x2 sv = __builtin_amdgcn_cvt_pk_f32_fp8((int)h8v[(size_t)v * 64 + lane], false);
    float acc0 = wself * sv[0];
    float acc1 = wself * sv[1];
    float wsum_own = 0.f;

    int ngro = (cnt + 7) >> 3;
    if (ngro > 0) {
        const uint4* epk = (const uint4*)(csr + beg);
        int u0[8], u1[8];
        float l_own0, l_own1;
        unsigned int x0[8], x1[8];
        {
            uint4 pk = epk[0];
            u0[0] = pk.x & 0xffff; u0[1] = pk.x >> 16;
            u0[2] = pk.y & 0xffff; u0[3] = pk.y >> 16;
            u0[4] = pk.z & 0xffff; u0[5] = pk.z >> 16;
            u0[6] = pk.w & 0xffff; u0[7] = pk.w >> 16;
            unsigned int d = slot < 4 ? (slot < 2 ? pk.x : pk.y)
                                      : (slot < 6 ? pk.z : pk.w);
            int u_own = (slot & 1) ? (int)(d >> 16) : (int)(d & 0xffff);
            l_own0 = as[u_own * HEADS + hd];
            #pragma unroll
            for (int j = 0; j < 8; ++j) x0[j] = h8v[(size_t)u0[j] * 64 + lane];
        }
        for (int g = 0; g < ngro; ++g) {
            bool more = (g + 1 < ngro);
            if (more) {
                uint4 pk = epk[g + 1];
                u1[0] = pk.x & 0xffff; u1[1] = pk.x >> 16;
                u1[2] = pk.y & 0xffff; u1[3] = pk.y >> 16;
                u1[4] = pk.z & 0xffff; u1[5] = pk.z >> 16;
                u1[6] = pk.w & 0xffff; u1[7] = pk.w >> 16;
                unsigned int d = slot < 4 ? (slot < 2 ? pk.x : pk.y)
                                          : (slot < 6 ? pk.z : pk.w);
                int u_own = (slot & 1) ? (int)(d >> 16) : (int)(d & 0xffff);
                l_own1 = as[u_own * HEADS + hd];
                #pragma unroll
                for (int j = 0; j < 8; ++j) x1[j] = h8v[(size_t)u1[j] * 64 + lane];
            }
            float w_own = __expf(lrelu(l_own0 + adv));
            if (g * 8 + slot >= cnt) w_own = 0.f;
            wsum_own += w_own;
            #pragma unroll
            for (int j = 0; j < 8; ++j) {
                float wj = __shfl(w_own, gbase + j, 64);
                f32x2 hv2 = __builtin_amdgcn_cvt_pk_f32_fp8((int)x0[j], false);
                acc0 += wj * hv2[0];
                acc1 += wj * hv2[1];
            }
            if (more) {
                l_own0 = l_own1;
                #pragma unroll
                for (int j = 0; j < 8; ++j) { u0[j] = u1[j]; x0[j] = x1[j]; }
            }
        }
    }

    #pragma unroll
    for (int off = 1; off < 8; off <<= 1) wsum_own += __shfl_xor(wsum_own, off);
    float denom = wself + wsum_own;

    float inv = 1.f / (denom + 1e-16f);
    int c = 2 * lane;
    float o0 = fmaxf(acc0 * inv + bias[c], 0.f);
    float o1 = fmaxf(acc1 * inv + bias[c + 1], 0.f);
    ((unsigned int*)out)[(size_t)v * 64 + lane] =
        (unsigned int)f2bf(o0) | ((unsigned int)f2bf(o1) << 16);
}

// ================================================================ pool + FC head (R6-proven fused)
__global__ __launch_bounds__(256) void pool_head(const ushort* __restrict__ h,
    const int* __restrict__ batch,
    const float* __restrict__ bns_fc, const float* __restrict__ fc_w,
    const float* __restrict__ fc_b, const float* __restrict__ bn_hid,
    const float* __restrict__ w_class, const float* __restrict__ b_class,
    float* __restrict__ out)
{
    __shared__ float sred[256];
    __shared__ float v1[HIDD];
    __shared__ float v2[HIDD];
    __shared__ float lg[NCLS];
    __shared__ float lse;
    __shared__ int bounds[2];
    int gb = blockIdx.x, t = threadIdx.x;

    if (t < 2) {
        int key = gb + t;
        int lo = 0, hi = NN;
        while (lo < hi) {
            int mid = (lo + hi) >> 1;
            if (batch[mid] < key) lo = mid + 1; else hi = mid;
        }
        bounds[t] = lo;
    }
    __syncthreads();
    int beg = bounds[0], end = bounds[1];

    int half = t >> 7, c = t & 127;
    float a0 = 0.f, a1 = 0.f, a2 = 0.f, a3 = 0.f;
    int r = beg + half;
    for (; r + 6 < end; r += 8) {
        a0 += bf2f(h[(size_t)r * HIDD + c]);
        a1 += bf2f(h[(size_t)(r + 2) * HIDD + c]);
        a2 += bf2f(h[(size_t)(r + 4) * HIDD + c]);
        a3 += bf2f(h[(size_t)(r + 6) * HIDD + c]);
    }
    for (; r < end; r += 2) a0 += bf2f(h[(size_t)r * HIDD + c]);
    sred[t] = (a0 + a1) + (a2 + a3);
    __syncthreads();

    if (t < HIDD) {
        float gv = sred[t] + sred[t + 128];
        float gamma = bns_fc[t], beta = bns_fc[HIDD + t];
        float mu = bns_fc[2 * HIDD + t], var = bns_fc[3 * HIDD + t];
        v1[t] = (gv - mu) * gamma * rsqrtf(var + EPSS) + beta;
    }
    __syncthreads();

    if (t < HIDD) {
        float acc = fc_b[t];
        for (int k = 0; k < HIDD; ++k) acc += v1[k] * fc_w[k * HIDD + t];
        acc = fmaxf(acc, 0.f);
        float gamma = bn_hid[t], beta = bn_hid[HIDD + t];
        float mu = bn_hid[2 * HIDD + t], var = bn_hid[3 * HIDD + t];
        v2[t] = (acc - mu) * gamma * rsqrtf(var + EPSS) + beta;
    }
    __syncthreads();

    if (t < NCLS) {
        float acc2 = b_class[t];
        for (int k = 0; k < HIDD; ++k) acc2 += v2[k] * w_class[k * NCLS + t];
        lg[t] = acc2;
    }
    __syncthreads();
    if (t == 0) {
        float mx = lg[0];
        for (int i = 1; i < NCLS; ++i) mx = fmaxf(mx, lg[i]);
        float ss = 0.f;
        for (int i = 0; i < NCLS; ++i) ss += __expf(lg[i] - mx);
        lse = mx + __logf(ss);
    }
    __syncthreads();
    if (t < NCLS) out[gb * NCLS + t] = lg[t] - lse;
}

// ================================================================ launch (9 dispatches)
extern "C" void kernel_launch(void* const* d_in, const int* in_sizes, int n_in,
                              void* d_out, int out_size, void* d_ws, size_t ws_size,
                              hipStream_t stream)
{
    const float* x        = (const float*)d_in[0];
    const int*   edge     = (const int*)d_in[1];
    const int*   batch    = (const int*)d_in[2];
    const float* bn_feat  = (const float*)d_in[3];
    const float* w_feat   = (const float*)d_in[4];
    const float* b_feat   = (const float*)d_in[5];
    const float* bns_conv = (const float*)d_in[6];
    const float* gat_w    = (const float*)d_in[7];
    const float* att_src  = (const float*)d_in[8];
    const float* att_dst  = (const float*)d_in[9];
    const float* gat_b    = (const float*)d_in[10];
    const float* bns_fc   = (const float*)d_in[11];
    const float* fc_w     = (const float*)d_in[12];
    const float* fc_b     = (const float*)d_in[13];
    const float* bn_hid   = (const float*)d_in[14];
    const float* w_class  = (const float*)d_in[15];
    const float* b_class  = (const float*)d_in[16];
    float* out = (float*)d_out;
    (void)in_sizes; (void)n_in; (void)out_size; (void)ws_size;

    char* ws = (char*)d_ws;
    size_t off = 0;
    auto alloc = [&](size_t bytes) {
        void* p = ws + off;
        off = (off + bytes + 255) & ~(size_t)255;
        return p;
    };
    ushort* Wt        = (ushort*)alloc((size_t)4 * WSTRIDE * sizeof(ushort));
    float*  bp        = (float*)alloc(4 * BSTRIDE * sizeof(float));
    ushort* h_a       = (ushort*)alloc((size_t)NN * HIDD * sizeof(ushort));
    unsigned char* h8 = (unsigned char*)alloc((size_t)NN * HIDD);
    float*  alph_s    = (float*)alloc((size_t)NN * HEADS * sizeof(float));
    float*  alph_d    = (float*)alloc((size_t)NN * HEADS * sizeof(float));
    int*    tab       = (int*)alloc((size_t)BIN_BLOCKS * TABW * sizeof(int));
    unsigned int* tmp = (unsigned int*)alloc((size_t)E_EDGES * sizeof(unsigned int));
    unsigned int* rowptr = (unsigned int*)alloc((size_t)NN * sizeof(unsigned int));
    ushort* csr       = (ushort*)alloc((size_t)NB * CAPB * sizeof(ushort) + 64);

    const int* src = edge;
    const int* dst = edge + E_EDGES;

    prep_bin<<<279, 256, 0, stream>>>(bn_feat, w_feat, b_feat, bns_conv, gat_w,
                                      att_src, att_dst, src, dst, Wt, bp, tmp, tab);
    sort_gemm0<<<NB + GTILES, 256, 0, stream>>>(tab, tmp, csr, rowptr,
                                                x, Wt, bp, h_a);

    for (int i = 0; i < NCONV; ++i) {
        gemm_conv<<<GTILES, 256, 0, stream>>>(h_a,
            Wt + (size_t)(i + 1) * WSTRIDE, bp + (i + 1) * BSTRIDE, h8,
            alph_s, alph_d);
        gat_aggregate<<<(NN + 3) / 4, 256, 0, stream>>>(h8, alph_s, alph_d,
                                                        rowptr, csr, gat_b + i * HIDD, h_a);
    }

    pool_head<<<NGG, 256, 0, stream>>>(h_a, batch, bns_fc, fc_w, fc_b, bn_hid,
                                       w_class, b_class, out);
}

// Round 16
// 313.707 us; speedup vs baseline: 1.6369x; 1.0119x over previous
//
#include <hip/hip_runtime.h>

#define NN 50000
#define E_EDGES 800000
#define F_INN 128
#define HIDD 128
#define HEADS 8
#define CDIM 16
#define NCLS 10
#define NGG 64
#define NCONV 3
#define EPSS 1e-5f
#define NEG_SLOPE 0.2f

// Wt layout: per layer 144 rows (output cols) x 128 k, bf16.
#define WROWS 144
#define WSTRIDE (WROWS * 128)
#define BSTRIDE 144

// bucket partition: 128 dst nodes per bucket
#define BSH 7
#define BSZ 128
#define NB ((NN + BSZ - 1) / BSZ)   // 391
#define BIN_BLOCKS 256
#define BIN_CHUNK (E_EDGES / BIN_BLOCKS)   // 3125 exact
#define TABW 392                     // 391 offsets + sentinel
#define CAPB 4608                    // fixed csr region/bucket
#define SORT_BUF 4608
#define PW_KCH 32
#define GTILES ((NN + 127) / 128)    // 391 gemm blocks (128 rows each)
#define TPITCH 132                   // fp8 LDS tile row pitch (pad 4)

typedef __attribute__((ext_vector_type(8))) short short8;
typedef __attribute__((ext_vector_type(4))) float f32x4;
typedef __attribute__((ext_vector_type(2))) float f32x2;

__device__ __forceinline__ float lrelu(float x) { return x > 0.f ? x : NEG_SLOPE * x; }

__device__ __forceinline__ float bf2f(ushort u) {
    union { unsigned int i; float f; } v;
    v.i = ((unsigned int)u) << 16;
    return v.f;
}
__device__ __forceinline__ ushort f2bf(float f) {
    union { float f; unsigned int i; } v;
    v.f = f;
    unsigned int r = (v.i + 0x7fffu + ((v.i >> 16) & 1u)) >> 16;  // RNE
    return (ushort)r;
}
// OCP e4m3 encode via HW pack (saturating); take byte 0
__device__ __forceinline__ unsigned char f2fp8(float f) {
    int r = __builtin_amdgcn_cvt_pk_fp8_f32(f, f, 0, false);
    return (unsigned char)(r & 0xff);
}

// ================================================================ GEMM core (bf16-out path, layer 0 only)
__device__ __forceinline__ void gemm_core_l0(int tile, int t,
    const float* __restrict__ Ain, const ushort* __restrict__ Wt,
    const float* __restrict__ bias, ushort* __restrict__ Out, int n)
{
    int wave = t >> 6, lane = t & 63;
    int m16 = lane & 15, quad = lane >> 4;
    int rbase = tile * 128 + wave * 32;

    short8 afrag[2][4];
    #pragma unroll
    for (int tt = 0; tt < 2; ++tt) {
        int arow_i = rbase + tt * 16 + m16;
        size_t arow = (size_t)(arow_i < n ? arow_i : 0) * HIDD + quad * 8;
        const float* ap = Ain + arow;
        #pragma unroll
        for (int kk = 0; kk < 4; ++kk) {
            float4 lo = *(const float4*)(ap + kk * 32);
            float4 hi = *(const float4*)(ap + kk * 32 + 4);
            short8 f;
            f[0] = (short)f2bf(lo.x); f[1] = (short)f2bf(lo.y);
            f[2] = (short)f2bf(lo.z); f[3] = (short)f2bf(lo.w);
            f[4] = (short)f2bf(hi.x); f[5] = (short)f2bf(hi.y);
            f[6] = (short)f2bf(hi.z); f[7] = (short)f2bf(hi.w);
            afrag[tt][kk] = f;
        }
    }

    f32x4 acc[2][8];
    #pragma unroll
    for (int tt = 0; tt < 2; ++tt)
        #pragma unroll
        for (int nt = 0; nt < 8; ++nt) acc[tt][nt] = (f32x4){0.f, 0.f, 0.f, 0.f};

    #pragma unroll
    for (int nt = 0; nt < 8; ++nt) {
        const ushort* brow = Wt + (size_t)(nt * 16 + m16) * HIDD + quad * 8;
        #pragma unroll
        for (int kk = 0; kk < 4; ++kk) {
            short8 bfrag = *(const short8*)(brow + kk * 32);
            acc[0][nt] = __builtin_amdgcn_mfma_f32_16x16x32_bf16(afrag[0][kk], bfrag, acc[0][nt], 0, 0, 0);
            acc[1][nt] = __builtin_amdgcn_mfma_f32_16x16x32_bf16(afrag[1][kk], bfrag, acc[1][nt], 0, 0, 0);
        }
    }

    #pragma unroll
    for (int tt = 0; tt < 2; ++tt) {
        int tb = rbase + tt * 16;
        #pragma unroll
        for (int nt = 0; nt < 8; ++nt) {
            int col = nt * 16 + m16;
            float bv = bias[col];
            #pragma unroll
            for (int r = 0; r < 4; ++r) {
                int orow = tb + quad * 4 + r;
                if (orow < n) {
                    float v = fmaxf(acc[tt][nt][r] + bv, 0.f);
                    Out[(size_t)orow * HIDD + col] = f2bf(v);
                }
            }
        }
    }
}

// ================================================================ kernel A: prep + bin (R14-proven)
__global__ __launch_bounds__(256) void prep_bin(
    const float* __restrict__ bn_feat, const float* __restrict__ w_feat,
    const float* __restrict__ b_feat, const float* __restrict__ bns_conv,
    const float* __restrict__ gat_w, const float* __restrict__ att_src,
    const float* __restrict__ att_dst, const int* __restrict__ src,
    const int* __restrict__ dst, ushort* __restrict__ Wt,
    float* __restrict__ bp, unsigned int* __restrict__ tmp, int* __restrict__ tab)
{
    __shared__ __align__(16) char smem[18560];
    int blk = blockIdx.x;
    int t = threadIdx.x;

    if (blk < 16) {
        float* Wl = (float*)smem;            // 32*129 floats
        float* aak = Wl + PW_KCH * 129;
        int layer = blk >> 2;
        int k0 = (blk & 3) * PW_KCH;
        const float* bn; const float* W;
        if (layer == 0) { bn = bn_feat; W = w_feat; }
        else { bn = bns_conv + (layer - 1) * 4 * HIDD; W = gat_w + (size_t)(layer - 1) * HIDD * HIDD; }
        if (t < PW_KCH) {
            int k = k0 + t;
            aak[t] = bn[k] * rsqrtf(bn[3 * HIDD + k] + EPSS);
        }
        for (int i = t; i < PW_KCH * 128; i += 256) {
            int kk = i >> 7, n = i & 127;
            Wl[kk * 129 + n] = W[(size_t)(k0 + kk) * 128 + n];
        }
        __syncthreads();
        ushort* wrow = Wt + (size_t)layer * WSTRIDE;
        for (int i = t; i < 128 * PW_KCH; i += 256) {
            int n = i >> 5, kk = i & 31;
            wrow[n * 128 + k0 + kk] = f2bf(aak[kk] * Wl[kk * 129 + n]);
        }
    } else if (blk < 20) {
        float* ccs = (float*)smem;
        int layer = blk - 16;
        const float* bn; const float* W;
        if (layer == 0) { bn = bn_feat; W = w_feat; }
        else { bn = bns_conv + (layer - 1) * 4 * HIDD; W = gat_w + (size_t)(layer - 1) * HIDD * HIDD; }
        if (t < 128) {
            float a = bn[t] * rsqrtf(bn[3 * HIDD + t] + EPSS);
            ccs[t] = bn[HIDD + t] - bn[2 * HIDD + t] * a;
        }
        __syncthreads();
        if (t < 128) {
            float bacc = (layer == 0) ? b_feat[t] : 0.f;
            for (int k = 0; k < 128; ++k) bacc += ccs[k] * W[(size_t)k * 128 + t];
            bp[layer * BSTRIDE + t] = bacc;
        }
    } else if (blk < 23) {
        float* Wl   = (float*)smem;               // 32*129 floats (16512 B)
        float* redS = (float*)(smem + 16512);     // 256 floats
        float* redD = redS + 256;
        int li = blk - 20;
        int L = li + 1;
        const float* bn = bns_conv + li * 4 * HIDD;
        const float* W  = gat_w + (size_t)li * HIDD * HIDD;
        const float* as = att_src + li * HEADS * CDIM;
        const float* ad = att_dst + li * HEADS * CDIM;
        ushort* Wo = Wt + (size_t)L * WSTRIDE;
        int kl = t >> 3, h = t & 7;
        float acc_s = 0.f, acc_d = 0.f;
        for (int c0 = 0; c0 < 4; ++c0) {
            int k0 = c0 * 32;
            __syncthreads();
            for (int i = t; i < 32 * 128; i += 256) {
                int kk = i >> 7, n = i & 127;
                Wl[kk * 129 + n] = W[(size_t)(k0 + kk) * 128 + n];
            }
            __syncthreads();
            int k = k0 + kl;
            float a  = bn[k] * rsqrtf(bn[3 * HIDD + k] + EPSS);
            float cc = bn[HIDD + k] - bn[2 * HIDD + k] * a;
            float ps = 0.f, pd = 0.f;
            #pragma unroll
            for (int c = 0; c < 16; ++c) {
                float wv = Wl[kl * 129 + h * 16 + c];
                ps += wv * as[h * 16 + c];
                pd += wv * ad[h * 16 + c];
            }
            Wo[(128 + h) * 128 + k] = f2bf(a * ps);
            Wo[(136 + h) * 128 + k] = f2bf(a * pd);
            acc_s += cc * ps;
            acc_d += cc * pd;
        }
        redS[t] = acc_s; redD[t] = acc_d;
        __syncthreads();
        if (t < 8) {
            float s = 0.f, d = 0.f;
            for (int q = 0; q < 32; ++q) { s += redS[q * 8 + t]; d += redD[q * 8 + t]; }
            bp[L * BSTRIDE + 128 + t] = s;
            bp[L * BSTRIDE + 136 + t] = d;
        }
    } else {
        unsigned int* stage = (unsigned int*)smem;        // 3125 entries (12500 B)
        int* hist = (int*)(smem + 12512);                 // 392 ints
        int* A    = hist + TABW;                          // 512 ints (scan)
        int k = blk - 23;
        int cbeg = k * BIN_CHUNK;
        int cend = cbeg + BIN_CHUNK;

        for (int i = t; i < TABW; i += 256) hist[i] = 0;
        __syncthreads();
        for (int e = cbeg + t; e < cend; e += 256)
            atomicAdd(&hist[dst[e] >> BSH], 1);
        __syncthreads();
        int i1 = t + 256;
        int c0 = hist[t];
        int c1 = (i1 < TABW) ? hist[i1] : 0;
        A[t] = c0; A[i1] = c1;
        __syncthreads();
        for (int d = 1; d < 512; d <<= 1) {
            int a0 = (t >= d) ? A[t - d] : 0;
            int a1 = A[i1 - d];
            __syncthreads();
            A[t] += a0; A[i1] += a1;
            __syncthreads();
        }
        int e0 = A[t] - c0;
        int e1 = A[i1] - c1;
        tab[(size_t)k * TABW + t] = e0;
        if (i1 < TABW) tab[(size_t)k * TABW + i1] = e1;
        hist[t] = e0;
        if (i1 < TABW) hist[i1] = e1;
        __syncthreads();
        for (int e = cbeg + t; e < cend; e += 256) {
            int d = dst[e];
            int b = d >> BSH;
            unsigned int pk = ((unsigned int)(d & (BSZ - 1)) << 16) | (unsigned int)src[e];
            int p = atomicAdd(&hist[b], 1);
            stage[p] = pk;
        }
        __syncthreads();
        for (int i = t; i < BIN_CHUNK; i += 256)
            tmp[(size_t)k * BIN_CHUNK + i] = stage[i];
    }
}

// ================================================================ kernel B: sort (391) + GEMM layer0 (391)  [R14-proven]
__global__ __launch_bounds__(256) void sort_gemm0(
    const int* __restrict__ tab, const unsigned int* __restrict__ tmp,
    ushort* __restrict__ csr, unsigned int* __restrict__ rowptr,
    const float* __restrict__ x, const ushort* __restrict__ Wt,
    const float* __restrict__ bp, ushort* __restrict__ h_a)
{
    int t = threadIdx.x;
    if (blockIdx.x < NB) {
        __shared__ unsigned int buf[SORT_BUF];   // 18432 B
        __shared__ int sc[256];
        __shared__ int o0s[256];
        __shared__ int hist[BSZ], pex[BSZ], cur[BSZ];
        int b = blockIdx.x;
        int base_out = b * CAPB;

        int o0 = tab[(size_t)t * TABW + b];
        int o1 = tab[(size_t)t * TABW + b + 1];
        int c = o1 - o0;
        o0s[t] = o0;
        sc[t] = c;
        __syncthreads();
        for (int d = 1; d < 256; d <<= 1) {
            int a = (t >= d) ? sc[t - d] : 0;
            __syncthreads();
            sc[t] += a;
            __syncthreads();
        }
        int m = sc[255];
        int mybase = sc[t] - c;
        if (m > CAPB - BSZ * 7) m = CAPB - BSZ * 7;
        for (int j = 0; j < c; ++j) {
            int p = mybase + j;
            if (p < m) buf[p] = tmp[(size_t)t * BIN_CHUNK + o0s[t] + j];
        }
        if (t < BSZ) hist[t] = 0;
        __syncthreads();
        for (int i = t; i < m; i += 256) atomicAdd(&hist[buf[i] >> 16], 1);
        __syncthreads();
        int pd = 0;
        if (t < BSZ) { pd = (hist[t] + 7) & ~7; pex[t] = pd; }
        __syncthreads();
        for (int d = 1; d < BSZ; d <<= 1) {
            int a = (t < BSZ && t >= d) ? pex[t - d] : 0;
            __syncthreads();
            if (t < BSZ) pex[t] += a;
            __syncthreads();
        }
        if (t < BSZ) {
            int ex = pex[t] - pd;
            pex[t] = ex;
            cur[t] = ex;
            int node = b * BSZ + t;
            if (node < NN)
                rowptr[node] = (unsigned int)(base_out + ex) | ((unsigned int)hist[t] << 21);
        }
        __syncthreads();
        for (int i = t; i < m; i += 256) {
            unsigned int pk = buf[i];
            int dl = pk >> 16;
            int p = atomicAdd(&cur[dl], 1);
            csr[base_out + p] = (ushort)(pk & 0xffffu);
        }
        __syncthreads();
        if (t < BSZ) {
            int ex = pex[t], hn = hist[t], pdn = (hn + 7) & ~7;
            for (int i = hn; i < pdn; ++i) csr[base_out + ex + i] = 0;
        }
    } else {
        gemm_core_l0(blockIdx.x - NB, t, x, Wt, bp, h_a, NN);
    }
}

// ================================================================ conv GEMM (layers 1-3): fp8 + alphas
// h8 output LDS-staged: epilogue writes bytes to a 128x132 LDS tile, then the
// block dumps it with fully-coalesced dwordx4 stores (16 store-transactions
// per wave instead of ~256 one-byte 16B-segment stores — R15 epilogue was
// store-transaction-bound).
__global__ __launch_bounds__(256) void gemm_conv(const ushort* __restrict__ Ain,
    const ushort* __restrict__ Wt, const float* __restrict__ bias,
    unsigned char* __restrict__ h8, float* __restrict__ alph_s,
    float* __restrict__ alph_d)
{
    __shared__ unsigned char tile[128 * TPITCH];   // ~16.9 KB
    int t = threadIdx.x;
    int wave = t >> 6, lane = t & 63;
    int m16 = lane & 15, quad = lane >> 4;
    int tile0 = blockIdx.x * 128;
    int rbase = tile0 + wave * 32;
    const int n = NN;

    short8 afrag[2][4];
    #pragma unroll
    for (int tt = 0; tt < 2; ++tt) {
        int arow_i = rbase + tt * 16 + m16;
        size_t arow = (size_t)(arow_i < n ? arow_i : 0) * HIDD + quad * 8;
        const ushort* ap = Ain + arow;
        #pragma unroll
        for (int kk = 0; kk < 4; ++kk)
            afrag[tt][kk] = *(const short8*)(ap + kk * 32);
    }

    f32x4 acc[2][9];
    #pragma unroll
    for (int tt = 0; tt < 2; ++tt)
        #pragma unroll
        for (int nt = 0; nt < 9; ++nt) acc[tt][nt] = (f32x4){0.f, 0.f, 0.f, 0.f};

    #pragma unroll
    for (int nt = 0; nt < 9; ++nt) {
        const ushort* brow = Wt + (size_t)(nt * 16 + m16) * HIDD + quad * 8;
        #pragma unroll
        for (int kk = 0; kk < 4; ++kk) {
            short8 bfrag = *(const short8*)(brow + kk * 32);
            acc[0][nt] = __builtin_amdgcn_mfma_f32_16x16x32_bf16(afrag[0][kk], bfrag, acc[0][nt], 0, 0, 0);
            acc[1][nt] = __builtin_amdgcn_mfma_f32_16x16x32_bf16(afrag[1][kk], bfrag, acc[1][nt], 0, 0, 0);
        }
    }

    #pragma unroll
    for (int tt = 0; tt < 2; ++tt) {
        int lrow = wave * 32 + tt * 16;
        #pragma unroll
        for (int nt = 0; nt < 8; ++nt) {
            int col = nt * 16 + m16;
            float bv = bias[col];
            #pragma unroll
            for (int r = 0; r < 4; ++r) {
                float v = acc[tt][nt][r] + bv;
                tile[(lrow + quad * 4 + r) * TPITCH + col] = f2fp8(v);
            }
        }
        {
            float bv = bias[128 + m16];
            int tb = rbase + tt * 16;
            #pragma unroll
            for (int r = 0; r < 4; ++r) {
                int orow = tb + quad * 4 + r;
                if (orow < n) {
                    float v = acc[tt][8][r] + bv;
                    if (m16 < 8) alph_s[orow * HEADS + m16] = v;
                    else         alph_d[orow * HEADS + (m16 - 8)] = v;
                }
            }
        }
    }
    __syncthreads();
    // coalesced dump: thread = (row = t>>1, half = t&1), 64 B each
    {
        int row = t >> 1, half = t & 1;
        int orow = tile0 + row;
        if (orow < n) {
            const unsigned char* srcp = &tile[row * TPITCH + half * 64];
            uint4* dstp = (uint4*)(h8 + (size_t)orow * HIDD + half * 64);
            #pragma unroll
            for (int j = 0; j < 4; ++j)
                dstp[j] = *(const uint4*)(srcp + j * 16);
        }
    }
}

// ================================================================ GAT aggregation (R15-proven, all-fp8)
__global__ __launch_bounds__(256) void gat_aggregate(
    const unsigned char* __restrict__ h8,
    const float* __restrict__ as, const float* __restrict__ ad,
    const unsigned int* __restrict__ rowptr, const ushort* __restrict__ csr,
    const float* __restrict__ bias, ushort* __restrict__ out)
{
    int wid = (blockIdx.x * 256 + threadIdx.x) >> 6;
    int v = __builtin_amdgcn_readfirstlane(wid);
    if (v >= NN) return;
    int lane = threadIdx.x & 63;
    int hd = lane >> 3;
    int slot = lane & 7;
    int gbase = lane & ~7;
    unsigned int rp = rowptr[v];
    int beg = rp & 0x1FFFFF;
    int cnt = rp >> 21;
    float adv = ad[v * HEADS + hd];

    const ushort* h8v = (const ushort*)h8;      // 2 fp8 channels per lane

    float wself = __expf(lrelu(as[v * HEADS + hd] + adv));
    f32x2 sv = __builtin_amdgcn_cvt_pk_f32_fp8((int)h8v[(size_t)v * 64 + lane], false);
    float acc0 = wself * sv[0];
    float acc1 = wself * sv[1];
    float wsum_own = 0.f;

    int ngro = (cnt + 7) >> 3;
    if (ngro > 0) {
        const uint4* epk = (const uint4*)(csr + beg);
        int u0[8], u1[8];
        float l_own0, l_own1;
        unsigned int x0[8], x1[8];
        {
            uint4 pk = epk[0];
            u0[0] = pk.x & 0xffff; u0[1] = pk.x >> 16;
            u0[2] = pk.y & 0xffff; u0[3] = pk.y >> 16;
            u0[4] = pk.z & 0xffff; u0[5] = pk.z >> 16;
            u0[6] = pk.w & 0xffff; u0[7] = pk.w >> 16;
            unsigned int d = slot < 4 ? (slot < 2 ? pk.x : pk.y)
                                      : (slot < 6 ? pk.z : pk.w);
            int u_own = (slot & 1) ? (int)(d >> 16) : (int)(d & 0xffff);
            l_own0 = as[u_own * HEADS + hd];
            #pragma unroll
            for (int j = 0; j < 8; ++j) x0[j] = h8v[(size_t)u0[j] * 64 + lane];
        }
        for (int g = 0; g < ngro; ++g) {
            bool more = (g + 1 < ngro);
            if (more) {
                uint4 pk = epk[g + 1];
                u1[0] = pk.x & 0xffff; u1[1] = pk.x >> 16;
                u1[2] = pk.y & 0xffff; u1[3] = pk.y >> 16;
                u1[4] = pk.z & 0xffff; u1[5] = pk.z >> 16;
                u1[6] = pk.w & 0xffff; u1[7] = pk.w >> 16;
                unsigned int d = slot < 4 ? (slot < 2 ? pk.x : pk.y)
                                          : (slot < 6 ? pk.z : pk.w);
                int u_own = (slot & 1) ? (int)(d >> 16) : (int)(d & 0xffff);
                l_own1 = as[u_own * HEADS + hd];
                #pragma unroll
                for (int j = 0; j < 8; ++j) x1[j] = h8v[(size_t)u1[j] * 64 + lane];
            }
            float w_own = __expf(lrelu(l_own0 + adv));
            if (g * 8 + slot >= cnt) w_own = 0.f;
            wsum_own += w_own;
            #pragma unroll
            for (int j = 0; j < 8; ++j) {
                float wj = __shfl(w_own, gbase + j, 64);
                f32x2 hv2 = __builtin_amdgcn_cvt_pk_f32_fp8((int)x0[j], false);
                acc0 += wj * hv2[0];
                acc1 += wj * hv2[1];
            }
            if (more) {
                l_own0 = l_own1;
                #pragma unroll
                for (int j = 0; j < 8; ++j) { u0[j] = u1[j]; x0[j] = x1[j]; }
            }
        }
    }

    #pragma unroll
    for (int off = 1; off < 8; off <<= 1) wsum_own += __shfl_xor(wsum_own, off);
    float denom = wself + wsum_own;

    float inv = 1.f / (denom + 1e-16f);
    int c = 2 * lane;
    float o0 = fmaxf(acc0 * inv + bias[c], 0.f);
    float o1 = fmaxf(acc1 * inv + bias[c + 1], 0.f);
    ((unsigned int*)out)[(size_t)v * 64 + lane] =
        (unsigned int)f2bf(o0) | ((unsigned int)f2bf(o1) << 16);
}

// ================================================================ pool + FC head (R6-proven fused)
__global__ __launch_bounds__(256) void pool_head(const ushort* __restrict__ h,
    const int* __restrict__ batch,
    const float* __restrict__ bns_fc, const float* __restrict__ fc_w,
    const float* __restrict__ fc_b, const float* __restrict__ bn_hid,
    const float* __restrict__ w_class, const float* __restrict__ b_class,
    float* __restrict__ out)
{
    __shared__ float sred[256];
    __shared__ float v1[HIDD];
    __shared__ float v2[HIDD];
    __shared__ float lg[NCLS];
    __shared__ float lse;
    __shared__ int bounds[2];
    int gb = blockIdx.x, t = threadIdx.x;

    if (t < 2) {
        int key = gb + t;
        int lo = 0, hi = NN;
        while (lo < hi) {
            int mid = (lo + hi) >> 1;
            if (batch[mid] < key) lo = mid + 1; else hi = mid;
        }
        bounds[t] = lo;
    }
    __syncthreads();
    int beg = bounds[0], end = bounds[1];

    int half = t >> 7, c = t & 127;
    float a0 = 0.f, a1 = 0.f, a2 = 0.f, a3 = 0.f;
    int r = beg + half;
    for (; r + 6 < end; r += 8) {
        a0 += bf2f(h[(size_t)r * HIDD + c]);
        a1 += bf2f(h[(size_t)(r + 2) * HIDD + c]);
        a2 += bf2f(h[(size_t)(r + 4) * HIDD + c]);
        a3 += bf2f(h[(size_t)(r + 6) * HIDD + c]);
    }
    for (; r < end; r += 2) a0 += bf2f(h[(size_t)r * HIDD + c]);
    sred[t] = (a0 + a1) + (a2 + a3);
    __syncthreads();

    if (t < HIDD) {
        float gv = sred[t] + sred[t + 128];
        float gamma = bns_fc[t], beta = bns_fc[HIDD + t];
        float mu = bns_fc[2 * HIDD + t], var = bns_fc[3 * HIDD + t];
        v1[t] = (gv - mu) * gamma * rsqrtf(var + EPSS) + beta;
    }
    __syncthreads();

    if (t < HIDD) {
        float acc = fc_b[t];
        for (int k = 0; k < HIDD; ++k) acc += v1[k] * fc_w[k * HIDD + t];
        acc = fmaxf(acc, 0.f);
        float gamma = bn_hid[t], beta = bn_hid[HIDD + t];
        float mu = bn_hid[2 * HIDD + t], var = bn_hid[3 * HIDD + t];
        v2[t] = (acc - mu) * gamma * rsqrtf(var + EPSS) + beta;
    }
    __syncthreads();

    if (t < NCLS) {
        float acc2 = b_class[t];
        for (int k = 0; k < HIDD; ++k) acc2 += v2[k] * w_class[k * NCLS + t];
        lg[t] = acc2;
    }
    __syncthreads();
    if (t == 0) {
        float mx = lg[0];
        for (int i = 1; i < NCLS; ++i) mx = fmaxf(mx, lg[i]);
        float ss = 0.f;
        for (int i = 0; i < NCLS; ++i) ss += __expf(lg[i] - mx);
        lse = mx + __logf(ss);
    }
    __syncthreads();
    if (t < NCLS) out[gb * NCLS + t] = lg[t] - lse;
}

// ================================================================ launch (9 dispatches)
extern "C" void kernel_launch(void* const* d_in, const int* in_sizes, int n_in,
                              void* d_out, int out_size, void* d_ws, size_t ws_size,
                              hipStream_t stream)
{
    const float* x        = (const float*)d_in[0];
    const int*   edge     = (const int*)d_in[1];
    const int*   batch    = (const int*)d_in[2];
    const float* bn_feat  = (const float*)d_in[3];
    const float* w_feat   = (const float*)d_in[4];
    const float* b_feat   = (const float*)d_in[5];
    const float* bns_conv = (const float*)d_in[6];
    const float* gat_w    = (const float*)d_in[7];
    const float* att_src  = (const float*)d_in[8];
    const float* att_dst  = (const float*)d_in[9];
    const float* gat_b    = (const float*)d_in[10];
    const float* bns_fc   = (const float*)d_in[11];
    const float* fc_w     = (const float*)d_in[12];
    const float* fc_b     = (const float*)d_in[13];
    const float* bn_hid   = (const float*)d_in[14];
    const float* w_class  = (const float*)d_in[15];
    const float* b_class  = (const float*)d_in[16];
    float* out = (float*)d_out;
    (void)in_sizes; (void)n_in; (void)out_size; (void)ws_size;

    char* ws = (char*)d_ws;
    size_t off = 0;
    auto alloc = [&](size_t bytes) {
        void* p = ws + off;
        off = (off + bytes + 255) & ~(size_t)255;
        return p;
    };
    ushort* Wt        = (ushort*)alloc((size_t)4 * WSTRIDE * sizeof(ushort));
    float*  bp        = (float*)alloc(4 * BSTRIDE * sizeof(float));
    ushort* h_a       = (ushort*)alloc((size_t)NN * HIDD * sizeof(ushort));
    unsigned char* h8 = (unsigned char*)alloc((size_t)NN * HIDD);
    float*  alph_s    = (float*)alloc((size_t)NN * HEADS * sizeof(float));
    float*  alph_d    = (float*)alloc((size_t)NN * HEADS * sizeof(float));
    int*    tab       = (int*)alloc((size_t)BIN_BLOCKS * TABW * sizeof(int));
    unsigned int* tmp = (unsigned int*)alloc((size_t)E_EDGES * sizeof(unsigned int));
    unsigned int* rowptr = (unsigned int*)alloc((size_t)NN * sizeof(unsigned int));
    ushort* csr       = (ushort*)alloc((size_t)NB * CAPB * sizeof(ushort) + 64);

    const int* src = edge;
    const int* dst = edge + E_EDGES;

    prep_bin<<<279, 256, 0, stream>>>(bn_feat, w_feat, b_feat, bns_conv, gat_w,
                                      att_src, att_dst, src, dst, Wt, bp, tmp, tab);
    sort_gemm0<<<NB + GTILES, 256, 0, stream>>>(tab, tmp, csr, rowptr,
                                                x, Wt, bp, h_a);

    for (int i = 0; i < NCONV; ++i) {
        gemm_conv<<<GTILES, 256, 0, stream>>>(h_a,
            Wt + (size_t)(i + 1) * WSTRIDE, bp + (i + 1) * BSTRIDE, h8,
            alph_s, alph_d);
        gat_aggregate<<<(NN + 3) / 4, 256, 0, stream>>>(h8, alph_s, alph_d,
                                                        rowptr, csr, gat_b + i * HIDD, h_a);
    }

    pool_head<<<NGG, 256, 0, stream>>>(h_a, batch, bns_fc, fc_w, fc_b, bn_hid,
                                       w_class, b_class, out);
}